// Round 10
// baseline (131934.290 us; speedup 1.0000x reference)
//
#include <hip/hip_runtime.h>
#include <math.h>

#define NN 60000
#define BB 8
#define GS 7500   // nodes per graph
#define FF 384
#define EE 600000
#define HH 6
#define CC 10
#define HT_BITS 20
#define HT_SIZE (1u << HT_BITS)
#define HT_MASK (HT_SIZE - 1u)
#define TPB 256
#define CAP 80000  // per-graph edge capacity
#define REMW ((GS + 31) / 32)
#define GPAD 32    // counter padding: one per 128B (R3 lesson)
#define SCAN_B 1024
#define NBLK ((NN + SCAN_B - 1) / SCAN_B)  // 59
static_assert(NBLK <= 64, "scan3 wave-scan assumes <=64 blocks");
static_assert((HH % 2) == 0 && (CC % 2) == 0, "float2 paths assume even fd");

static inline int ngrid(int n) { return (n + TPB - 1) / TPB; }

// ---------- helpers ----------
__device__ __forceinline__ unsigned long long mkprio(float sc, int e) {
  return (((unsigned long long)__float_as_uint(sc)) << 32) |
         (unsigned int)(~(unsigned int)e);
}

// ---------- stage 1 matmul: h1pre = x @ W1 ----------
__global__ void k_mm1(const float* __restrict__ x, const float* __restrict__ W,
                      float* __restrict__ out) {
  __shared__ float Ws[FF * HH];
  for (int i = threadIdx.x; i < FF * HH; i += blockDim.x) Ws[i] = W[i];
  __syncthreads();
  int wave = threadIdx.x >> 6, lane = threadIdx.x & 63;
  int node = blockIdx.x * 4 + wave;
  if (node >= NN) return;
  const float* xr = x + (size_t)node * FF;
  float acc[HH] = {0.f, 0.f, 0.f, 0.f, 0.f, 0.f};
  for (int k = lane; k < FF; k += 64) {
    float xv = xr[k];
#pragma unroll
    for (int j = 0; j < HH; j++) acc[j] += xv * Ws[k * HH + j];
  }
#pragma unroll
  for (int j = 0; j < HH; j++) {
#pragma unroll
    for (int o = 32; o > 0; o >>= 1) acc[j] += __shfl_down(acc[j], o, 64);
  }
  if (lane == 0) {
#pragma unroll
    for (int j = 0; j < HH; j++) out[(size_t)node * HH + j] = acc[j];
  }
}

// ---------- fused per-stage init ----------
__global__ void k_prep(float* __restrict__ deg, unsigned char* __restrict__ hasloop,
                       int* __restrict__ gcntsA,
                       int* __restrict__ gcntsB, float* __restrict__ gsum,
                       float* __restrict__ gcnt, const unsigned char* __restrict__ nvin,
                       unsigned char* __restrict__ nvout, float* __restrict__ scale,
                       int* __restrict__ merged, int* __restrict__ partner,
                       unsigned long long* __restrict__ bestA,
                       unsigned long long* __restrict__ bestB,
                       unsigned char* __restrict__ remG) {
  int v = blockIdx.x * blockDim.x + threadIdx.x;
  if (v >= NN) return;
  deg[v] = 0.f;
  hasloop[v] = 0;
  unsigned char nvv = nvin ? nvin[v] : 1;
  nvout[v] = nvv;
  remG[v] = nvv;
  bestA[v] = 0ULL;
  bestB[v] = 0ULL;
  scale[v] = 1.0f;
  if (merged) merged[v] = -1;
  partner[v] = -1;
  if (v < BB * GPAD) { gcntsA[v] = 0; gcntsB[v] = 0; }
  if (v < BB * CC) gsum[v] = 0.f;
  if (v < BB) gcnt[v] = 0.f;
}

// ---------- generic GCN conv pieces ----------
__global__ void k_deg(const int* __restrict__ src, const int* __restrict__ dst,
                      const unsigned char* __restrict__ ev, float* __restrict__ deg,
                      unsigned char* __restrict__ hasloop) {
  int e = blockIdx.x * blockDim.x + threadIdx.x;
  if (e >= EE) return;
  if (ev && !ev[e]) return;
  int d = dst[e];
  atomicAdd(&deg[d], 1.0f);
  if (src[e] == d) hasloop[d] = 1;
}

// ---------- CSR build: scan of deg -> rowstart, then scatter ----------
__global__ __launch_bounds__(1024) void k_scan1(const float* __restrict__ deg,
                                                int* __restrict__ rowstart,
                                                int* __restrict__ bsum) {
  __shared__ int tmp[SCAN_B];
  int t = threadIdx.x;
  int i = blockIdx.x * SCAN_B + t;
  int v = (i < NN) ? (int)deg[i] : 0;
  tmp[t] = v;
  __syncthreads();
  for (int o = 1; o < SCAN_B; o <<= 1) {
    int y = (t >= o) ? tmp[t - o] : 0;
    __syncthreads();
    tmp[t] += y;
    __syncthreads();
  }
  if (i < NN) rowstart[i] = tmp[t] - v;  // exclusive within block
  if (t == SCAN_B - 1) bsum[blockIdx.x] = tmp[t];
}

// scan fixup (each block wave-scans the 59 block sums itself) + fused dinv/addloop
__global__ void k_scan3(int* __restrict__ rowstart, const int* __restrict__ bsum,
                        int* __restrict__ fill, const float* __restrict__ deg,
                        const unsigned char* __restrict__ hasloop,
                        const unsigned char* __restrict__ nv, float* __restrict__ dinv,
                        unsigned char* __restrict__ addloop) {
  __shared__ int offs[64];
  __shared__ int total;
  int t = threadIdx.x;
  if (t < 64) {
    int v = (t < NBLK) ? bsum[t] : 0;
    int x = v;
#pragma unroll
    for (int o = 1; o < 64; o <<= 1) {
      int y = __shfl_up(x, o, 64);
      if (t >= o) x += y;
    }
    offs[t] = x - v;          // exclusive block offset
    if (t == 63) total = x;   // grand total
  }
  __syncthreads();
  int i = blockIdx.x * blockDim.x + t;
  if (i >= NN) return;
  int r = rowstart[i] + offs[i >> 10];  // SCAN_B == 1024
  rowstart[i] = r;
  fill[i] = r;
  if (i == NN - 1) rowstart[NN] = total;
  int nvv = nv ? (int)nv[i] : 1;
  unsigned char al = (nvv && !hasloop[i]) ? 1 : 0;
  float d = deg[i] + (float)al;
  dinv[i] = d > 0.f ? 1.0f / sqrtf(fmaxf(d, 1e-12f)) : 0.f;
  addloop[i] = al;
}

__global__ void k_scatter(const int* __restrict__ src, const int* __restrict__ dst,
                          const unsigned char* __restrict__ ev, int* __restrict__ fill,
                          int* __restrict__ csrS, int* __restrict__ csrE) {
  int e = blockIdx.x * blockDim.x + threadIdx.x;
  if (e >= EE) return;
  if (ev && !ev[e]) return;
  int d = dst[e];
  int p = atomicAdd(&fill[d], 1);
  csrS[p] = src[e];
  csrE[p] = e;
}

// fused gather aggregation + finalize; float2 gathers (rows 8B-aligned, FP order unchanged)
template <int FD>
__global__ void k_agg_fin(const int* __restrict__ rowstart, const int* __restrict__ csrS,
                          const float* __restrict__ dinv, const unsigned char* __restrict__ addloop,
                          const float* __restrict__ h, const float* __restrict__ b,
                          float* __restrict__ out, int relu) {
  int v = blockIdx.x * blockDim.x + threadIdx.x;
  if (v >= NN) return;
  int b0 = rowstart[v], b1 = rowstart[v + 1];
  float acc[FD];
#pragma unroll
  for (int j = 0; j < FD; j++) acc[j] = 0.f;
  float dv = dinv[v];
  for (int i = b0; i < b1; i++) {
    int s = csrS[i];
    float c = dinv[s] * dv;  // per-edge coef, matches reference factoring
    const float2* hr2 = (const float2*)(h + (size_t)s * FD);
#pragma unroll
    for (int j = 0; j < FD / 2; j++) {
      float2 hv = hr2[j];
      acc[2 * j] += hv.x * c;
      acc[2 * j + 1] += hv.y * c;
    }
  }
  float cl = addloop[v] ? dv * dv : 0.f;
  const float* hv = h + (size_t)v * FD;
#pragma unroll
  for (int j = 0; j < FD; j++) {
    float o = acc[j] + cl * hv[j] + b[j];
    if (relu) o = fmaxf(o, 0.f);
    out[(size_t)v * FD + j] = o;
  }
}

// ---------- edge pool: scores (also zeroes chosen[]); float2 row loads ----------
__global__ void k_raw(const float* __restrict__ x, const int* __restrict__ src,
                      const int* __restrict__ dst, const unsigned char* __restrict__ ev,
                      const float* __restrict__ Wp, const float* __restrict__ bp,
                      float* __restrict__ raw, unsigned char* __restrict__ chosen, int fd) {
  int e = blockIdx.x * blockDim.x + threadIdx.x;
  if (e >= EE) return;
  chosen[e] = 0;
  if (ev && !ev[e]) return;
  int s = src[e], d = dst[e];
  float r = bp[0];
  const float2* xs = (const float2*)(x + (size_t)s * fd);
  const float2* xd = (const float2*)(x + (size_t)d * fd);
  int h2 = fd >> 1;
  for (int j = 0; j < h2; j++) {
    float2 v = xs[j];
    r += v.x * Wp[2 * j];
    r += v.y * Wp[2 * j + 1];
  }
  for (int j = 0; j < h2; j++) {
    float2 v = xd[j];
    r += v.x * Wp[fd + 2 * j];
    r += v.y * Wp[fd + 2 * j + 1];
  }
  raw[e] = r;
}

// fused softmax stats + score + bestA posting (R6-verified form, untagged prios).
__global__ void k_smscore(const int* __restrict__ rowstart, const int* __restrict__ csrS,
                          const int* __restrict__ csrE, const float* __restrict__ raw,
                          const unsigned char* __restrict__ remG, float* __restrict__ score,
                          unsigned long long* __restrict__ bestA) {
  int v = blockIdx.x * blockDim.x + threadIdx.x;
  if (v >= NN) return;
  int b0 = rowstart[v], b1 = rowstart[v + 1];
  if (b0 == b1) return;
  float m = -INFINITY;
  for (int i = b0; i < b1; i++) m = fmaxf(m, raw[csrE[i]]);
  float s = 0.f;
  for (int i = b0; i < b1; i++) s += expf(raw[csrE[i]] - m);
  if (!remG[v]) return;
  float sd = s > 0.f ? s : 1.0f;
  unsigned long long lb = 0ULL;
  for (int i = b0; i < b1; i++) {
    int sv = csrS[i];
    if (!remG[sv]) continue;
    int e = csrE[i];
    float sc = expf(raw[e] - m) / sd + 0.5f;
    score[e] = sc;
    unsigned long long p = mkprio(sc, e);
    if (p > lb) lb = p;
    if (sv != v && p > bestA[sv]) atomicMax(&bestA[sv], p);
  }
  if (lb > bestA[v]) atomicMax(&bestA[v], lb);
}

// ---------- round 1 select + compact; survivors zero bestB ----------
__global__ void k_r1sel(const int* __restrict__ src, const int* __restrict__ dst,
                        const float* __restrict__ score, const unsigned char* __restrict__ ev,
                        unsigned char* __restrict__ remG,
                        const unsigned long long* __restrict__ bestA,
                        unsigned long long* __restrict__ bestB,
                        unsigned char* __restrict__ chosen, ulonglong2* __restrict__ recs,
                        int* __restrict__ gcnts) {
  __shared__ int wcnt[TPB / 64][BB];
  __shared__ int bbase[BB];
  int e = blockIdx.x * blockDim.x + threadIdx.x;
  int w = threadIdx.x >> 6, lane = threadIdx.x & 63;
  int keep = 0, s = 0, d = 0, g = 0;
  unsigned long long p = 0;
  if (e < EE && (!ev || ev[e])) {
    s = src[e];
    d = dst[e];
    g = s / GS;
    if (remG[s] && remG[d]) {
      p = mkprio(score[e], e);
      if (bestA[s] == p && bestA[d] == p) {
        chosen[e] = 1;
        remG[s] = 0;
        remG[d] = 0;
      } else {
        keep = 1;
        bestB[s] = 0ULL;  // benign write race; next round's buffer
        bestB[d] = 0ULL;
      }
    }
  }
  int myrank = 0;
#pragma unroll
  for (int gg = 0; gg < BB; gg++) {
    unsigned long long m = __ballot(keep && g == gg);
    if (keep && g == gg) myrank = __popcll(m & ((1ULL << lane) - 1ULL));
    if (lane == 0) wcnt[w][gg] = __popcll(m);
  }
  __syncthreads();
  if (threadIdx.x < BB) {
    int gg = threadIdx.x, tot = 0;
#pragma unroll
    for (int ww = 0; ww < TPB / 64; ww++) {
      int c = wcnt[ww][gg];
      wcnt[ww][gg] = tot;
      tot += c;
    }
    bbase[gg] = tot ? atomicAdd(&gcnts[gg * GPAD], tot) : 0;
  }
  __syncthreads();
  if (keep)
    recs[(size_t)g * CAP + bbase[g] + wcnt[w][g] + myrank] =
        make_ulonglong2(p, (((unsigned long long)(unsigned int)s) << 32) | (unsigned int)d);
}

// ---------- generic global round (full GPU) over compacted lists ----------
// R7 lesson: do NOT fuse post into the select kernel. R9 lesson: do NOT use
// cooperative grid.sync (forces L2 flush on gfx950 -> 100MB refetch/round).
__global__ void k_gpost(const ulonglong2* __restrict__ recs, const int* __restrict__ gcnts,
                        const unsigned char* __restrict__ remG,
                        unsigned long long* __restrict__ bestC, int* __restrict__ gcntsOut) {
  int g = blockIdx.y;
  if (blockIdx.x == 0 && threadIdx.x == 0) gcntsOut[g * GPAD] = 0;
  int n = gcnts[g * GPAD];
  const ulonglong2* lst = recs + (size_t)g * CAP;
  int stride = gridDim.x * blockDim.x;
  for (int i = blockIdx.x * blockDim.x + threadIdx.x; i < n; i += stride) {
    ulonglong2 r = lst[i];
    int s = (int)(r.y >> 32), d = (int)(r.y & 0xFFFFFFFFu);
    if (remG[s] && remG[d]) {
      if (r.x > bestC[s]) atomicMax(&bestC[s], r.x);
      if (d != s && r.x > bestC[d]) atomicMax(&bestC[d], r.x);
    }
  }
}

// sel: winners commit; survivors -> out list + zero bestN (next buffer)
__global__ void k_gsel(const ulonglong2* __restrict__ recsIn, const int* __restrict__ gcntsIn,
                       unsigned char* __restrict__ remG,
                       const unsigned long long* __restrict__ bestC,
                       unsigned long long* __restrict__ bestN,
                       unsigned char* __restrict__ chosen, ulonglong2* __restrict__ recsOut,
                       int* __restrict__ gcntsOut) {
  int g = blockIdx.y;
  int n = gcntsIn[g * GPAD];
  const ulonglong2* lst = recsIn + (size_t)g * CAP;
  ulonglong2* outl = recsOut + (size_t)g * CAP;
  int lane = threadIdx.x & 63;
  int stride = gridDim.x * blockDim.x;
  for (int i = blockIdx.x * blockDim.x + threadIdx.x; i - lane < n; i += stride) {
    int keep = 0;
    ulonglong2 r;
    if (i < n) {
      r = lst[i];
      int s = (int)(r.y >> 32), d = (int)(r.y & 0xFFFFFFFFu);
      if (remG[s] && remG[d]) {
        if (bestC[s] == r.x && bestC[d] == r.x) {
          int e = (int)(~(unsigned int)(r.x & 0xFFFFFFFFu));
          chosen[e] = 1;
          remG[s] = 0;
          remG[d] = 0;
        } else {
          keep = 1;
          bestN[s] = 0ULL;
          bestN[d] = 0ULL;
        }
      }
    }
    unsigned long long m = __ballot(keep);
    int tot = __popcll(m);
    int pre = __popcll(m & ((1ULL << lane) - 1ULL));
    int b0 = 0;
    if (lane == 0 && tot) b0 = atomicAdd(&gcntsOut[g * GPAD], tot);
    b0 = __shfl(b0, 0, 64);
    if (keep) outl[b0 + pre] = r;
  }
}

// ---------- matching tail: per-graph LDS fixpoint ----------
// Barrier discipline (R2/R3 lesson): three __syncthreads per round; the one after
// the clear protects the cnt_next read/reset handoff. Reg-cached path (n<=4096):
// records loaded ONCE per round, P3 clear from register-known survivors — same
// clear-set as the streaming survivor-driven clear.
__global__ __launch_bounds__(1024) void k_match_g(ulonglong2* __restrict__ recs0,
                                                  ulonglong2* __restrict__ recs1,
                                                  const int* __restrict__ gcnts,
                                                  const unsigned char* __restrict__ remG,
                                                  unsigned char* __restrict__ chosen) {
  __shared__ unsigned long long best[GS];
  __shared__ unsigned int remB[REMW];
  __shared__ int cnt_next;
  const int g = blockIdx.x;
  const int base = g * GS;
  const int t = threadIdx.x, nth = blockDim.x;
  const int lane = t & 63;

  for (int w = t; w < REMW; w += nth) {
    unsigned int bits = 0;
    int v0 = w * 32;
    if (v0 + 32 <= GS) {
      const unsigned int* p4 = (const unsigned int*)(remG + base + v0);
#pragma unroll
      for (int q = 0; q < 8; q++) {
        unsigned int x4 = p4[q];
        bits |= ((x4 & 1u) << (q * 4)) | (((x4 >> 8) & 1u) << (q * 4 + 1)) |
                (((x4 >> 16) & 1u) << (q * 4 + 2)) | (((x4 >> 24) & 1u) << (q * 4 + 3));
      }
    } else {
      for (int b = 0; b < 32; b++) {
        int v = v0 + b;
        if (v < GS) bits |= (remG[base + v] ? 1u : 0u) << b;
      }
    }
    remB[w] = bits;
  }
  for (int i = t; i < GS; i += nth) best[i] = 0ULL;
  __syncthreads();

  ulonglong2* bufs[2] = {recs0 + (size_t)g * CAP, recs1 + (size_t)g * CAP};
  int n = gcnts[g * GPAD];
  int cur = 0;
  int guard = 0;

  while (n > 0) {
    if (++guard > 100000) break;  // dormant watchdog (practical rounds ~30)
    if (n <= nth * 4) {
      // ---- register-cached round: load once, reuse across all phases ----
      ulonglong2 r[4];
      int have[4], kept[4];
      int ls_[4], ld_[4];
#pragma unroll
      for (int k = 0; k < 4; k++) {
        int i = t + k * nth;
        have[k] = i < n;
        kept[k] = 0;
        if (have[k]) {
          r[k] = bufs[cur][i];
          ls_[k] = (int)(r[k].y >> 32) - base;
          ld_[k] = (int)(r[k].y & 0xFFFFFFFFu) - base;
        }
      }
      // P1: post priorities; drop records with dead endpoints
#pragma unroll
      for (int k = 0; k < 4; k++) {
        if (!have[k]) continue;
        int ls = ls_[k], ld = ld_[k];
        if (((remB[ls >> 5] >> (ls & 31)) & 1u) && ((remB[ld >> 5] >> (ld & 31)) & 1u)) {
          atomicMax(&best[ls], r[k].x);
          if (ld != ls) atomicMax(&best[ld], r[k].x);
        } else {
          have[k] = 0;
        }
      }
      if (t == 0) cnt_next = 0;
      __syncthreads();
      // P2: winners commit; survivors compact (no re-read of the list)
#pragma unroll
      for (int k = 0; k < 4; k++) {
        int keep = 0;
        if (have[k]) {
          int ls = ls_[k], ld = ld_[k];
          if (best[ls] == r[k].x && best[ld] == r[k].x) {
            int e = (int)(~(unsigned int)(r[k].x & 0xFFFFFFFFu));
            chosen[e] = 1;
            atomicAnd(&remB[ls >> 5], ~(1u << (ls & 31)));
            atomicAnd(&remB[ld >> 5], ~(1u << (ld & 31)));
          } else {
            keep = 1;
          }
        }
        kept[k] = keep;
        unsigned long long m = __ballot(keep);
        int tot = __popcll(m);
        int pre = __popcll(m & ((1ULL << lane) - 1ULL));
        int b0 = 0;
        if (lane == 0 && tot) b0 = atomicAdd(&cnt_next, tot);
        b0 = __shfl(b0, 0, 64);
        if (keep) bufs[cur ^ 1][b0 + pre] = r[k];
      }
      __syncthreads();
      n = cnt_next;
      // P3: clear best for survivors straight from registers (no global read)
#pragma unroll
      for (int k = 0; k < 4; k++) {
        if (kept[k]) {
          best[ls_[k]] = 0ULL;
          best[ld_[k]] = 0ULL;
        }
      }
      __syncthreads();  // protects cnt_next handoff + clears before next posts
    } else {
      // ---- streaming round (big n): R8-verified 3-pass form ----
      for (int i0 = 0; i0 < n; i0 += nth * 4) {
        ulonglong2 r[4];
        int have[4];
#pragma unroll
        for (int k = 0; k < 4; k++) {
          int i = i0 + t + k * nth;
          have[k] = i < n;
          if (have[k]) r[k] = bufs[cur][i];
        }
#pragma unroll
        for (int k = 0; k < 4; k++) {
          if (!have[k]) continue;
          int ls = (int)(r[k].y >> 32) - base, ld = (int)(r[k].y & 0xFFFFFFFFu) - base;
          if (((remB[ls >> 5] >> (ls & 31)) & 1u) && ((remB[ld >> 5] >> (ld & 31)) & 1u)) {
            atomicMax(&best[ls], r[k].x);
            if (ld != ls) atomicMax(&best[ld], r[k].x);
          }
        }
      }
      if (t == 0) cnt_next = 0;
      __syncthreads();
      for (int i0 = 0; i0 < n; i0 += nth * 4) {
        ulonglong2 r[4];
        int have[4];
#pragma unroll
        for (int k = 0; k < 4; k++) {
          int i = i0 + t + k * nth;
          have[k] = i < n;
          if (have[k]) r[k] = bufs[cur][i];
        }
#pragma unroll
        for (int k = 0; k < 4; k++) {
          int keep = 0;
          if (have[k]) {
            int ls = (int)(r[k].y >> 32) - base;
            int ld = (int)(r[k].y & 0xFFFFFFFFu) - base;
            if (((remB[ls >> 5] >> (ls & 31)) & 1u) && ((remB[ld >> 5] >> (ld & 31)) & 1u)) {
              if (best[ls] == r[k].x && best[ld] == r[k].x) {
                int e = (int)(~(unsigned int)(r[k].x & 0xFFFFFFFFu));
                chosen[e] = 1;
                atomicAnd(&remB[ls >> 5], ~(1u << (ls & 31)));
                atomicAnd(&remB[ld >> 5], ~(1u << (ld & 31)));
              } else {
                keep = 1;
              }
            }
          }
          unsigned long long m = __ballot(keep);
          int tot = __popcll(m);
          int pre = __popcll(m & ((1ULL << lane) - 1ULL));
          int b0 = 0;
          if (lane == 0 && tot) b0 = atomicAdd(&cnt_next, tot);
          b0 = __shfl(b0, 0, 64);
          if (keep) bufs[cur ^ 1][b0 + pre] = r[k];
        }
      }
      __syncthreads();
      n = cnt_next;
      // P3: hybrid clear
      if (n < 4096) {
        for (int i = t; i < n; i += nth) {
          ulonglong2 r = bufs[cur ^ 1][i];
          best[(int)(r.y >> 32) - base] = 0ULL;
          best[(int)(r.y & 0xFFFFFFFFu) - base] = 0ULL;
        }
      } else {
        for (int i = t; i < GS; i += nth) best[i] = 0ULL;
      }
      __syncthreads();
    }
    cur ^= 1;
  }
}

// ---------- edge pool: post-matching ----------
__global__ void k_pool_edge(const int* __restrict__ src, const int* __restrict__ dst,
                            const unsigned char* __restrict__ chosen, const float* __restrict__ score,
                            unsigned char* __restrict__ nvout, float* __restrict__ scale,
                            int* __restrict__ partner, int* __restrict__ merged) {
  int e = blockIdx.x * blockDim.x + threadIdx.x;
  if (e >= EE) return;
  if (!chosen[e]) return;
  int s = src[e], d = dst[e];
  scale[s] = score[e];
  if (merged) merged[d] = s;
  if (s != d) {
    nvout[d] = 0;
    partner[s] = d;
  }
}

// fused: newx1 (never materialized) -> h2pre = newx1 @ W2
__global__ void k_newx_mm2(const float* __restrict__ h1, const int* __restrict__ partner,
                           const float* __restrict__ scale, const unsigned char* __restrict__ nvout,
                           const float* __restrict__ W2, float* __restrict__ h2pre) {
  int v = blockIdx.x * blockDim.x + threadIdx.x;
  if (v >= NN) return;
  float sc = scale[v];
  int ok = nvout[v];
  int p = partner[v];
  float nx[HH];
#pragma unroll
  for (int j = 0; j < HH; j++) {
    float a = h1[(size_t)v * HH + j];
    if (p >= 0) a += h1[(size_t)p * HH + j];
    nx[j] = ok ? a * sc : 0.f;
  }
#pragma unroll
  for (int c = 0; c < CC; c++) {
    float a = 0.f;
#pragma unroll
    for (int j = 0; j < HH; j++) a += nx[j] * W2[j * CC + c];
    h2pre[(size_t)v * CC + c] = a;
  }
}

// fused remap + dedup insert
__device__ __forceinline__ unsigned int ht_hash(unsigned long long key) {
  return (unsigned int)((key * 0x9E3779B97F4A7C15ULL) >> 44) & HT_MASK;
}

__global__ void k_remap_ins(const int* __restrict__ src, const int* __restrict__ dst,
                            const int* __restrict__ merged, int* __restrict__ ns,
                            int* __restrict__ nd, unsigned long long* __restrict__ htab) {
  int e = blockIdx.x * blockDim.x + threadIdx.x;
  if (e >= EE) return;
  int s = src[e], d = dst[e];
  int ms = merged[s], md = merged[d];
  int a = ms >= 0 ? ms : s;
  int b = md >= 0 ? md : d;
  ns[e] = a;
  nd[e] = b;
  unsigned long long key =
      (unsigned long long)((((unsigned int)a) << 16) | (unsigned int)b);
  unsigned long long val = (key << 32) | (unsigned int)e;
  unsigned int h = ht_hash(key);
  for (;;) {
    unsigned long long curv = htab[h];
    if (curv == ~0ULL) {
      unsigned long long prev = atomicCAS(&htab[h], ~0ULL, val);
      if (prev == ~0ULL) break;
      curv = prev;
    }
    if ((curv >> 32) == key) {
      if ((curv & 0xFFFFFFFFULL) > (unsigned long long)(unsigned int)e)
        atomicMin(&htab[h], val);
      break;
    }
    h = (h + 1) & HT_MASK;
  }
}

// fused dedup-mark + stage2 degree count (same edge domain; deg pre-zeroed by k_prep)
__global__ void k_dedup_deg(const int* __restrict__ ns, const int* __restrict__ nd,
                            const unsigned long long* __restrict__ htab,
                            unsigned char* __restrict__ evout, float* __restrict__ deg,
                            unsigned char* __restrict__ hasloop) {
  int e = blockIdx.x * blockDim.x + threadIdx.x;
  if (e >= EE) return;
  unsigned long long key =
      (unsigned long long)((((unsigned int)ns[e]) << 16) | (unsigned int)nd[e]);
  unsigned int h = ht_hash(key);
  for (;;) {
    unsigned long long curv = htab[h];
    if ((curv >> 32) == key) {
      unsigned char ev = ((curv & 0xFFFFFFFFULL) == (unsigned long long)(unsigned int)e) ? 1 : 0;
      evout[e] = ev;
      if (ev) {
        int d = nd[e];
        atomicAdd(&deg[d], 1.0f);
        if (ns[e] == d) hasloop[d] = 1;
      }
      return;
    }
    h = (h + 1) & HT_MASK;
  }
}

// fused: newx2 (never materialized) -> graph mean-pool accumulate
__global__ void k_newx_pool(const float* __restrict__ h2, const int* __restrict__ partner,
                            const float* __restrict__ scale, const unsigned char* __restrict__ nv,
                            float* __restrict__ gsum, float* __restrict__ gcnt) {
  int v = blockIdx.x * blockDim.x + threadIdx.x;
  int lane = threadIdx.x & 63;
  int b = (v < NN ? v : NN - 1) / GS;
  int active = (v < NN) && nv[v];
  float cnt = active ? 1.f : 0.f;
  float val[CC];
  if (active) {
    float sc = scale[v];
    int p = partner[v];
    for (int j = 0; j < CC; j++) {
      float a = h2[(size_t)v * CC + j];
      if (p >= 0) a += h2[(size_t)p * CC + j];
      val[j] = a * sc;
    }
  } else {
    for (int j = 0; j < CC; j++) val[j] = 0.f;
  }
  int b0 = __shfl(b, 0, 64);
  unsigned long long same = __ballot(b == b0);
  if (same == ~0ULL) {
    for (int o = 32; o > 0; o >>= 1) {
      cnt += __shfl_down(cnt, o, 64);
      for (int j = 0; j < CC; j++) val[j] += __shfl_down(val[j], o, 64);
    }
    if (lane == 0 && cnt > 0.f) {
      atomicAdd(&gcnt[b0], cnt);
      for (int j = 0; j < CC; j++) atomicAdd(&gsum[b0 * CC + j], val[j]);
    }
  } else if (active) {
    atomicAdd(&gcnt[b], cnt);
    for (int j = 0; j < CC; j++) atomicAdd(&gsum[b * CC + j], val[j]);
  }
}

__global__ void k_logsm(const float* __restrict__ gsum, const float* __restrict__ gcnt,
                        float* __restrict__ out) {
  int t = threadIdx.x;
  if (t >= BB) return;
  float gr[CC];
  float c = gcnt[t];
  float m = -INFINITY;
  for (int j = 0; j < CC; j++) {
    gr[j] = gsum[t * CC + j] / c;
    m = fmaxf(m, gr[j]);
  }
  float s = 0.f;
  for (int j = 0; j < CC; j++) s += expf(gr[j] - m);
  float l = logf(s);
  for (int j = 0; j < CC; j++) out[t * CC + j] = gr[j] - m - l;
}

// ---------- host ----------
extern "C" void kernel_launch(void* const* d_in, const int* in_sizes, int n_in,
                              void* d_out, int out_size, void* d_ws, size_t ws_size,
                              hipStream_t stream) {
  const float* x = (const float*)d_in[0];
  const int* src = (const int*)d_in[1];
  const int* dst = (const int*)d_in[2];
  const float* W1 = (const float*)d_in[4];
  const float* b1 = (const float*)d_in[5];
  const float* W2 = (const float*)d_in[6];
  const float* b2 = (const float*)d_in[7];
  const float* Wp1 = (const float*)d_in[8];
  const float* bp1 = (const float*)d_in[9];
  const float* Wp2 = (const float*)d_in[10];
  const float* bp2 = (const float*)d_in[11];
  float* out = (float*)d_out;

  char* wsb = (char*)d_ws;
  size_t off = 0;
  auto A = [&](size_t bytes) -> char* {
    char* r = wsb + off;
    off = (off + bytes + 255) & ~(size_t)255;
    return r;
  };
  float* h1pre = (float*)A((size_t)NN * HH * 4);
  float* h1out = (float*)A((size_t)NN * HH * 4);
  float* deg = (float*)A((size_t)NN * 4);
  float* dinv = (float*)A((size_t)NN * 4);
  unsigned char* hasloop = (unsigned char*)A(NN);
  unsigned char* addloop = (unsigned char*)A(NN);
  float* raw = (float*)A((size_t)EE * 4);
  float* score = (float*)A((size_t)EE * 4);
  unsigned char* chosen = (unsigned char*)A(EE);
  unsigned char* nv1 = (unsigned char*)A(NN);
  unsigned char* nv2 = (unsigned char*)A(NN);
  float* scale = (float*)A((size_t)NN * 4);
  int* partner = (int*)A((size_t)NN * 4);
  int* merged = (int*)A((size_t)NN * 4);
  int* ns = (int*)A((size_t)EE * 4);
  int* nd = (int*)A((size_t)EE * 4);
  unsigned char* ev1 = (unsigned char*)A(EE);
  unsigned long long* htab = (unsigned long long*)A((size_t)HT_SIZE * 8);
  float* h2pre = (float*)A((size_t)NN * CC * 4);
  float* h2out = (float*)A((size_t)NN * CC * 4);
  unsigned long long* bestA = (unsigned long long*)A((size_t)NN * 8);
  unsigned long long* bestB = (unsigned long long*)A((size_t)NN * 8);
  unsigned char* remG = (unsigned char*)A(NN);
  ulonglong2* recs0 = (ulonglong2*)A((size_t)BB * CAP * 16);
  ulonglong2* recs1 = (ulonglong2*)A((size_t)BB * CAP * 16);
  int* gcntsA = (int*)A((size_t)BB * GPAD * 4);
  int* gcntsB = (int*)A((size_t)BB * GPAD * 4);
  float* gsum = (float*)A((size_t)BB * CC * 4);
  float* gcnt = (float*)A((size_t)BB * 4);
  int* rowstart = (int*)A((size_t)(NN + 1) * 4);
  int* fill = (int*)A((size_t)NN * 4);
  int* bsum = (int*)A((size_t)64 * 4);
  int* csrS = (int*)A((size_t)EE * 4);
  int* csrE = (int*)A((size_t)EE * 4);
  (void)ws_size; (void)n_in; (void)in_sizes; (void)out_size;

  const int GE = ngrid(EE), GN = ngrid(NN);
  const dim3 RG(32, BB);  // global-round grid: 32 blocks x 8 graphs

  // ===== stage 1: GCNConv(384->6) + ReLU =====
  hipMemsetAsync(htab, 0xFF, (size_t)HT_SIZE * 8, stream);
  hipLaunchKernelGGL(k_mm1, dim3((NN + 3) / 4), dim3(TPB), 0, stream, x, W1, h1pre);
  hipLaunchKernelGGL(k_prep, dim3(GN), dim3(TPB), 0, stream, deg, hasloop, gcntsA, gcntsB,
                     gsum, gcnt, (const unsigned char*)nullptr, nv1, scale, merged, partner, bestA, bestB, remG);
  hipLaunchKernelGGL(k_deg, dim3(GE), dim3(TPB), 0, stream, src, dst, (const unsigned char*)nullptr, deg, hasloop);
  hipLaunchKernelGGL(k_scan1, dim3(NBLK), dim3(SCAN_B), 0, stream, deg, rowstart, bsum);
  hipLaunchKernelGGL(k_scan3, dim3(GN), dim3(TPB), 0, stream, rowstart, bsum, fill, deg, hasloop,
                     (const unsigned char*)nullptr, dinv, addloop);
  hipLaunchKernelGGL(k_scatter, dim3(GE), dim3(TPB), 0, stream, src, dst, (const unsigned char*)nullptr, fill, csrS, csrE);
  hipLaunchKernelGGL(k_agg_fin<HH>, dim3(GN), dim3(TPB), 0, stream, rowstart, csrS, dinv, addloop, h1pre, b1, h1out, 1);

  // ===== edge pool 1 =====
  hipLaunchKernelGGL(k_raw, dim3(GE), dim3(TPB), 0, stream, h1out, src, dst, (const unsigned char*)nullptr, Wp1, bp1, raw, chosen, HH);
  hipLaunchKernelGGL(k_smscore, dim3(GN), dim3(TPB), 0, stream, rowstart, csrS, csrE, raw, remG, score, bestA);
  hipLaunchKernelGGL(k_r1sel, dim3(GE), dim3(TPB), 0, stream, src, dst, score, (const unsigned char*)nullptr, remG, bestA, bestB, chosen, recs0, gcntsA);
  // global rounds 2-6 (split post/sel — R7 lesson: fusing stalls commits)
  hipLaunchKernelGGL(k_gpost, RG, dim3(TPB), 0, stream, recs0, gcntsA, remG, bestB, gcntsB);
  hipLaunchKernelGGL(k_gsel, RG, dim3(TPB), 0, stream, recs0, gcntsA, remG, bestB, bestA, chosen, recs1, gcntsB);
  hipLaunchKernelGGL(k_gpost, RG, dim3(TPB), 0, stream, recs1, gcntsB, remG, bestA, gcntsA);
  hipLaunchKernelGGL(k_gsel, RG, dim3(TPB), 0, stream, recs1, gcntsB, remG, bestA, bestB, chosen, recs0, gcntsA);
  hipLaunchKernelGGL(k_gpost, RG, dim3(TPB), 0, stream, recs0, gcntsA, remG, bestB, gcntsB);
  hipLaunchKernelGGL(k_gsel, RG, dim3(TPB), 0, stream, recs0, gcntsA, remG, bestB, bestA, chosen, recs1, gcntsB);
  hipLaunchKernelGGL(k_gpost, RG, dim3(TPB), 0, stream, recs1, gcntsB, remG, bestA, gcntsA);
  hipLaunchKernelGGL(k_gsel, RG, dim3(TPB), 0, stream, recs1, gcntsB, remG, bestA, bestB, chosen, recs0, gcntsA);
  hipLaunchKernelGGL(k_gpost, RG, dim3(TPB), 0, stream, recs0, gcntsA, remG, bestB, gcntsB);
  hipLaunchKernelGGL(k_gsel, RG, dim3(TPB), 0, stream, recs0, gcntsA, remG, bestB, bestA, chosen, recs1, gcntsB);
  // LDS tail
  hipLaunchKernelGGL(k_match_g, dim3(BB), dim3(1024), 0, stream, recs1, recs0, gcntsB, remG, chosen);
  hipLaunchKernelGGL(k_pool_edge, dim3(GE), dim3(TPB), 0, stream, src, dst, chosen, score, nv1, scale, partner, merged);
  hipLaunchKernelGGL(k_newx_mm2, dim3(GN), dim3(TPB), 0, stream, h1out, partner, scale, nv1, W2, h2pre);
  hipLaunchKernelGGL(k_remap_ins, dim3(GE), dim3(TPB), 0, stream, src, dst, merged, ns, nd, htab);

  // ===== stage 2: GCNConv(6->10) =====
  hipLaunchKernelGGL(k_prep, dim3(GN), dim3(TPB), 0, stream, deg, hasloop, gcntsA, gcntsB,
                     gsum, gcnt, (const unsigned char*)nv1, nv2, scale, (int*)nullptr, partner, bestA, bestB, remG);
  hipLaunchKernelGGL(k_dedup_deg, dim3(GE), dim3(TPB), 0, stream, ns, nd, htab, ev1, deg, hasloop);
  hipLaunchKernelGGL(k_scan1, dim3(NBLK), dim3(SCAN_B), 0, stream, deg, rowstart, bsum);
  hipLaunchKernelGGL(k_scan3, dim3(GN), dim3(TPB), 0, stream, rowstart, bsum, fill, deg, hasloop,
                     (const unsigned char*)nv1, dinv, addloop);
  hipLaunchKernelGGL(k_scatter, dim3(GE), dim3(TPB), 0, stream, ns, nd, (const unsigned char*)ev1, fill, csrS, csrE);
  hipLaunchKernelGGL(k_agg_fin<CC>, dim3(GN), dim3(TPB), 0, stream, rowstart, csrS, dinv, addloop, h2pre, b2, h2out, 0);

  // ===== edge pool 2 =====
  hipLaunchKernelGGL(k_raw, dim3(GE), dim3(TPB), 0, stream, h2out, ns, nd, (const unsigned char*)ev1, Wp2, bp2, raw, chosen, CC);
  hipLaunchKernelGGL(k_smscore, dim3(GN), dim3(TPB), 0, stream, rowstart, csrS, csrE, raw, remG, score, bestA);
  hipLaunchKernelGGL(k_r1sel, dim3(GE), dim3(TPB), 0, stream, ns, nd, score, (const unsigned char*)ev1, remG, bestA, bestB, chosen, recs0, gcntsA);
  hipLaunchKernelGGL(k_gpost, RG, dim3(TPB), 0, stream, recs0, gcntsA, remG, bestB, gcntsB);
  hipLaunchKernelGGL(k_gsel, RG, dim3(TPB), 0, stream, recs0, gcntsA, remG, bestB, bestA, chosen, recs1, gcntsB);
  hipLaunchKernelGGL(k_gpost, RG, dim3(TPB), 0, stream, recs1, gcntsB, remG, bestA, gcntsA);
  hipLaunchKernelGGL(k_gsel, RG, dim3(TPB), 0, stream, recs1, gcntsB, remG, bestA, bestB, chosen, recs0, gcntsA);
  hipLaunchKernelGGL(k_gpost, RG, dim3(TPB), 0, stream, recs0, gcntsA, remG, bestB, gcntsB);
  hipLaunchKernelGGL(k_gsel, RG, dim3(TPB), 0, stream, recs0, gcntsA, remG, bestB, bestA, chosen, recs1, gcntsB);
  hipLaunchKernelGGL(k_gpost, RG, dim3(TPB), 0, stream, recs1, gcntsB, remG, bestA, gcntsA);
  hipLaunchKernelGGL(k_gsel, RG, dim3(TPB), 0, stream, recs1, gcntsB, remG, bestA, bestB, chosen, recs0, gcntsA);
  hipLaunchKernelGGL(k_gpost, RG, dim3(TPB), 0, stream, recs0, gcntsA, remG, bestB, gcntsB);
  hipLaunchKernelGGL(k_gsel, RG, dim3(TPB), 0, stream, recs0, gcntsA, remG, bestB, bestA, chosen, recs1, gcntsB);
  hipLaunchKernelGGL(k_match_g, dim3(BB), dim3(1024), 0, stream, recs1, recs0, gcntsB, remG, chosen);
  hipLaunchKernelGGL(k_pool_edge, dim3(GE), dim3(TPB), 0, stream, ns, nd, chosen, score, nv2, scale, partner, (int*)nullptr);

  // ===== readout =====
  hipLaunchKernelGGL(k_newx_pool, dim3(GN), dim3(TPB), 0, stream, h2out, partner, scale, nv2, gsum, gcnt);
  hipLaunchKernelGGL(k_logsm, dim3(1), dim3(64), 0, stream, gsum, gcnt, out);
}

// Round 11
// 1404.577 us; speedup vs baseline: 93.9317x; 93.9317x over previous
//
#include <hip/hip_runtime.h>
#include <math.h>

#define NN 60000
#define BB 8
#define GS 7500   // nodes per graph
#define FF 384
#define EE 600000
#define HH 6
#define CC 10
#define HT_BITS 20
#define HT_SIZE (1u << HT_BITS)
#define HT_MASK (HT_SIZE - 1u)
#define TPB 256
#define CAP 80000  // per-graph edge capacity
#define REMW ((GS + 31) / 32)
#define GPAD 32    // counter padding: one per 128B (R3 lesson)
#define SCAN_B 1024
#define NBLK ((NN + SCAN_B - 1) / SCAN_B)  // 59
static_assert(NBLK <= 64, "scan3 wave-scan assumes <=64 blocks");
static_assert((HH % 2) == 0 && (CC % 2) == 0, "float2 paths assume even fd");

static inline int ngrid(int n) { return (n + TPB - 1) / TPB; }

// ---------- helpers ----------
__device__ __forceinline__ unsigned long long mkprio(float sc, int e) {
  return (((unsigned long long)__float_as_uint(sc)) << 32) |
         (unsigned int)(~(unsigned int)e);
}

// ---------- stage 1 matmul: h1pre = x @ W1 ----------
__global__ void k_mm1(const float* __restrict__ x, const float* __restrict__ W,
                      float* __restrict__ out) {
  __shared__ float Ws[FF * HH];
  for (int i = threadIdx.x; i < FF * HH; i += blockDim.x) Ws[i] = W[i];
  __syncthreads();
  int wave = threadIdx.x >> 6, lane = threadIdx.x & 63;
  int node = blockIdx.x * 4 + wave;
  if (node >= NN) return;
  const float* xr = x + (size_t)node * FF;
  float acc[HH] = {0.f, 0.f, 0.f, 0.f, 0.f, 0.f};
  for (int k = lane; k < FF; k += 64) {
    float xv = xr[k];
#pragma unroll
    for (int j = 0; j < HH; j++) acc[j] += xv * Ws[k * HH + j];
  }
#pragma unroll
  for (int j = 0; j < HH; j++) {
#pragma unroll
    for (int o = 32; o > 0; o >>= 1) acc[j] += __shfl_down(acc[j], o, 64);
  }
  if (lane == 0) {
#pragma unroll
    for (int j = 0; j < HH; j++) out[(size_t)node * HH + j] = acc[j];
  }
}

// ---------- fused per-stage init ----------
__global__ void k_prep(float* __restrict__ deg, unsigned char* __restrict__ hasloop,
                       int* __restrict__ gcntsA,
                       int* __restrict__ gcntsB, float* __restrict__ gsum,
                       float* __restrict__ gcnt, const unsigned char* __restrict__ nvin,
                       unsigned char* __restrict__ nvout, float* __restrict__ scale,
                       int* __restrict__ merged, int* __restrict__ partner,
                       unsigned long long* __restrict__ bestA,
                       unsigned long long* __restrict__ bestB,
                       unsigned char* __restrict__ remG) {
  int v = blockIdx.x * blockDim.x + threadIdx.x;
  if (v >= NN) return;
  deg[v] = 0.f;
  hasloop[v] = 0;
  unsigned char nvv = nvin ? nvin[v] : 1;
  nvout[v] = nvv;
  remG[v] = nvv;
  bestA[v] = 0ULL;
  bestB[v] = 0ULL;
  scale[v] = 1.0f;
  if (merged) merged[v] = -1;
  partner[v] = -1;
  if (v < BB * GPAD) { gcntsA[v] = 0; gcntsB[v] = 0; }
  if (v < BB * CC) gsum[v] = 0.f;
  if (v < BB) gcnt[v] = 0.f;
}

// ---------- generic GCN conv pieces ----------
__global__ void k_deg(const int* __restrict__ src, const int* __restrict__ dst,
                      const unsigned char* __restrict__ ev, float* __restrict__ deg,
                      unsigned char* __restrict__ hasloop) {
  int e = blockIdx.x * blockDim.x + threadIdx.x;
  if (e >= EE) return;
  if (ev && !ev[e]) return;
  int d = dst[e];
  atomicAdd(&deg[d], 1.0f);
  if (src[e] == d) hasloop[d] = 1;
}

// ---------- CSR build: scan of deg -> rowstart, then scatter ----------
__global__ __launch_bounds__(1024) void k_scan1(const float* __restrict__ deg,
                                                int* __restrict__ rowstart,
                                                int* __restrict__ bsum) {
  __shared__ int tmp[SCAN_B];
  int t = threadIdx.x;
  int i = blockIdx.x * SCAN_B + t;
  int v = (i < NN) ? (int)deg[i] : 0;
  tmp[t] = v;
  __syncthreads();
  for (int o = 1; o < SCAN_B; o <<= 1) {
    int y = (t >= o) ? tmp[t - o] : 0;
    __syncthreads();
    tmp[t] += y;
    __syncthreads();
  }
  if (i < NN) rowstart[i] = tmp[t] - v;  // exclusive within block
  if (t == SCAN_B - 1) bsum[blockIdx.x] = tmp[t];
}

// scan fixup (each block wave-scans the 59 block sums itself) + fused dinv/addloop
__global__ void k_scan3(int* __restrict__ rowstart, const int* __restrict__ bsum,
                        int* __restrict__ fill, const float* __restrict__ deg,
                        const unsigned char* __restrict__ hasloop,
                        const unsigned char* __restrict__ nv, float* __restrict__ dinv,
                        unsigned char* __restrict__ addloop) {
  __shared__ int offs[64];
  __shared__ int total;
  int t = threadIdx.x;
  if (t < 64) {
    int v = (t < NBLK) ? bsum[t] : 0;
    int x = v;
#pragma unroll
    for (int o = 1; o < 64; o <<= 1) {
      int y = __shfl_up(x, o, 64);
      if (t >= o) x += y;
    }
    offs[t] = x - v;          // exclusive block offset
    if (t == 63) total = x;   // grand total
  }
  __syncthreads();
  int i = blockIdx.x * blockDim.x + t;
  if (i >= NN) return;
  int r = rowstart[i] + offs[i >> 10];  // SCAN_B == 1024
  rowstart[i] = r;
  fill[i] = r;
  if (i == NN - 1) rowstart[NN] = total;
  int nvv = nv ? (int)nv[i] : 1;
  unsigned char al = (nvv && !hasloop[i]) ? 1 : 0;
  float d = deg[i] + (float)al;
  dinv[i] = d > 0.f ? 1.0f / sqrtf(fmaxf(d, 1e-12f)) : 0.f;
  addloop[i] = al;
}

__global__ void k_scatter(const int* __restrict__ src, const int* __restrict__ dst,
                          const unsigned char* __restrict__ ev, int* __restrict__ fill,
                          int* __restrict__ csrS, int* __restrict__ csrE) {
  int e = blockIdx.x * blockDim.x + threadIdx.x;
  if (e >= EE) return;
  if (ev && !ev[e]) return;
  int d = dst[e];
  int p = atomicAdd(&fill[d], 1);
  csrS[p] = src[e];
  csrE[p] = e;
}

// fused gather aggregation + finalize; float2 gathers (rows 8B-aligned, FP order unchanged)
template <int FD>
__global__ void k_agg_fin(const int* __restrict__ rowstart, const int* __restrict__ csrS,
                          const float* __restrict__ dinv, const unsigned char* __restrict__ addloop,
                          const float* __restrict__ h, const float* __restrict__ b,
                          float* __restrict__ out, int relu) {
  int v = blockIdx.x * blockDim.x + threadIdx.x;
  if (v >= NN) return;
  int b0 = rowstart[v], b1 = rowstart[v + 1];
  float acc[FD];
#pragma unroll
  for (int j = 0; j < FD; j++) acc[j] = 0.f;
  float dv = dinv[v];
  for (int i = b0; i < b1; i++) {
    int s = csrS[i];
    float c = dinv[s] * dv;  // per-edge coef, matches reference factoring
    const float2* hr2 = (const float2*)(h + (size_t)s * FD);
#pragma unroll
    for (int j = 0; j < FD / 2; j++) {
      float2 hv = hr2[j];
      acc[2 * j] += hv.x * c;
      acc[2 * j + 1] += hv.y * c;
    }
  }
  float cl = addloop[v] ? dv * dv : 0.f;
  const float* hv = h + (size_t)v * FD;
#pragma unroll
  for (int j = 0; j < FD; j++) {
    float o = acc[j] + cl * hv[j] + b[j];
    if (relu) o = fmaxf(o, 0.f);
    out[(size_t)v * FD + j] = o;
  }
}

// ---------- edge pool: scores (also zeroes chosen[]); float2 row loads ----------
__global__ void k_raw(const float* __restrict__ x, const int* __restrict__ src,
                      const int* __restrict__ dst, const unsigned char* __restrict__ ev,
                      const float* __restrict__ Wp, const float* __restrict__ bp,
                      float* __restrict__ raw, unsigned char* __restrict__ chosen, int fd) {
  int e = blockIdx.x * blockDim.x + threadIdx.x;
  if (e >= EE) return;
  chosen[e] = 0;
  if (ev && !ev[e]) return;
  int s = src[e], d = dst[e];
  float r = bp[0];
  const float2* xs = (const float2*)(x + (size_t)s * fd);
  const float2* xd = (const float2*)(x + (size_t)d * fd);
  int h2 = fd >> 1;
  for (int j = 0; j < h2; j++) {
    float2 v = xs[j];
    r += v.x * Wp[2 * j];
    r += v.y * Wp[2 * j + 1];
  }
  for (int j = 0; j < h2; j++) {
    float2 v = xd[j];
    r += v.x * Wp[fd + 2 * j];
    r += v.y * Wp[fd + 2 * j + 1];
  }
  raw[e] = r;
}

// fused softmax stats + score + bestA posting (R6-verified form, untagged prios).
__global__ void k_smscore(const int* __restrict__ rowstart, const int* __restrict__ csrS,
                          const int* __restrict__ csrE, const float* __restrict__ raw,
                          const unsigned char* __restrict__ remG, float* __restrict__ score,
                          unsigned long long* __restrict__ bestA) {
  int v = blockIdx.x * blockDim.x + threadIdx.x;
  if (v >= NN) return;
  int b0 = rowstart[v], b1 = rowstart[v + 1];
  if (b0 == b1) return;
  float m = -INFINITY;
  for (int i = b0; i < b1; i++) m = fmaxf(m, raw[csrE[i]]);
  float s = 0.f;
  for (int i = b0; i < b1; i++) s += expf(raw[csrE[i]] - m);
  if (!remG[v]) return;
  float sd = s > 0.f ? s : 1.0f;
  unsigned long long lb = 0ULL;
  for (int i = b0; i < b1; i++) {
    int sv = csrS[i];
    if (!remG[sv]) continue;
    int e = csrE[i];
    float sc = expf(raw[e] - m) / sd + 0.5f;
    score[e] = sc;
    unsigned long long p = mkprio(sc, e);
    if (p > lb) lb = p;
    if (sv != v && p > bestA[sv]) atomicMax(&bestA[sv], p);
  }
  if (lb > bestA[v]) atomicMax(&bestA[v], lb);
}

// ---------- round 1 select + compact; survivors zero bestB ----------
__global__ void k_r1sel(const int* __restrict__ src, const int* __restrict__ dst,
                        const float* __restrict__ score, const unsigned char* __restrict__ ev,
                        unsigned char* __restrict__ remG,
                        const unsigned long long* __restrict__ bestA,
                        unsigned long long* __restrict__ bestB,
                        unsigned char* __restrict__ chosen, ulonglong2* __restrict__ recs,
                        int* __restrict__ gcnts) {
  __shared__ int wcnt[TPB / 64][BB];
  __shared__ int bbase[BB];
  int e = blockIdx.x * blockDim.x + threadIdx.x;
  int w = threadIdx.x >> 6, lane = threadIdx.x & 63;
  int keep = 0, s = 0, d = 0, g = 0;
  unsigned long long p = 0;
  if (e < EE && (!ev || ev[e])) {
    s = src[e];
    d = dst[e];
    g = s / GS;
    if (remG[s] && remG[d]) {
      p = mkprio(score[e], e);
      if (bestA[s] == p && bestA[d] == p) {
        chosen[e] = 1;
        remG[s] = 0;
        remG[d] = 0;
      } else {
        keep = 1;
        bestB[s] = 0ULL;  // benign write race; next round's buffer
        bestB[d] = 0ULL;
      }
    }
  }
  int myrank = 0;
#pragma unroll
  for (int gg = 0; gg < BB; gg++) {
    unsigned long long m = __ballot(keep && g == gg);
    if (keep && g == gg) myrank = __popcll(m & ((1ULL << lane) - 1ULL));
    if (lane == 0) wcnt[w][gg] = __popcll(m);
  }
  __syncthreads();
  if (threadIdx.x < BB) {
    int gg = threadIdx.x, tot = 0;
#pragma unroll
    for (int ww = 0; ww < TPB / 64; ww++) {
      int c = wcnt[ww][gg];
      wcnt[ww][gg] = tot;
      tot += c;
    }
    bbase[gg] = tot ? atomicAdd(&gcnts[gg * GPAD], tot) : 0;
  }
  __syncthreads();
  if (keep)
    recs[(size_t)g * CAP + bbase[g] + wcnt[w][g] + myrank] =
        make_ulonglong2(p, (((unsigned long long)(unsigned int)s) << 32) | (unsigned int)d);
}

// ---------- generic global round (full GPU) over compacted lists ----------
// R7 lesson: do NOT fuse post into the select kernel. R9 lesson: do NOT use
// cooperative grid.sync (forces L2 flush on gfx950 -> 100MB refetch/round).
__global__ void k_gpost(const ulonglong2* __restrict__ recs, const int* __restrict__ gcnts,
                        const unsigned char* __restrict__ remG,
                        unsigned long long* __restrict__ bestC, int* __restrict__ gcntsOut) {
  int g = blockIdx.y;
  if (blockIdx.x == 0 && threadIdx.x == 0) gcntsOut[g * GPAD] = 0;
  int n = gcnts[g * GPAD];
  const ulonglong2* lst = recs + (size_t)g * CAP;
  int stride = gridDim.x * blockDim.x;
  for (int i = blockIdx.x * blockDim.x + threadIdx.x; i < n; i += stride) {
    ulonglong2 r = lst[i];
    int s = (int)(r.y >> 32), d = (int)(r.y & 0xFFFFFFFFu);
    if (remG[s] && remG[d]) {
      if (r.x > bestC[s]) atomicMax(&bestC[s], r.x);
      if (d != s && r.x > bestC[d]) atomicMax(&bestC[d], r.x);
    }
  }
}

// sel: winners commit; survivors -> out list + zero bestN (next buffer)
__global__ void k_gsel(const ulonglong2* __restrict__ recsIn, const int* __restrict__ gcntsIn,
                       unsigned char* __restrict__ remG,
                       const unsigned long long* __restrict__ bestC,
                       unsigned long long* __restrict__ bestN,
                       unsigned char* __restrict__ chosen, ulonglong2* __restrict__ recsOut,
                       int* __restrict__ gcntsOut) {
  int g = blockIdx.y;
  int n = gcntsIn[g * GPAD];
  const ulonglong2* lst = recsIn + (size_t)g * CAP;
  ulonglong2* outl = recsOut + (size_t)g * CAP;
  int lane = threadIdx.x & 63;
  int stride = gridDim.x * blockDim.x;
  for (int i = blockIdx.x * blockDim.x + threadIdx.x; i - lane < n; i += stride) {
    int keep = 0;
    ulonglong2 r;
    if (i < n) {
      r = lst[i];
      int s = (int)(r.y >> 32), d = (int)(r.y & 0xFFFFFFFFu);
      if (remG[s] && remG[d]) {
        if (bestC[s] == r.x && bestC[d] == r.x) {
          int e = (int)(~(unsigned int)(r.x & 0xFFFFFFFFu));
          chosen[e] = 1;
          remG[s] = 0;
          remG[d] = 0;
        } else {
          keep = 1;
          bestN[s] = 0ULL;
          bestN[d] = 0ULL;
        }
      }
    }
    unsigned long long m = __ballot(keep);
    int tot = __popcll(m);
    int pre = __popcll(m & ((1ULL << lane) - 1ULL));
    int b0 = 0;
    if (lane == 0 && tot) b0 = atomicAdd(&gcntsOut[g * GPAD], tot);
    b0 = __shfl(b0, 0, 64);
    if (keep) outl[b0 + pre] = r;
  }
}

// ---------- matching tail: per-graph LDS fixpoint (R8-verified form, verbatim) ----------
// R2/R3 + R10 lesson: do NOT register-cache records across the P1/P2/P3 barriers
// (2/2 attempts degenerated to O(1)-commit rounds, ~1000x slower). Always re-read
// the list per phase. P3's clear doubles as the cnt_next handoff barrier.
__global__ __launch_bounds__(1024) void k_match_g(ulonglong2* __restrict__ recs0,
                                                  ulonglong2* __restrict__ recs1,
                                                  const int* __restrict__ gcnts,
                                                  const unsigned char* __restrict__ remG,
                                                  unsigned char* __restrict__ chosen) {
  __shared__ unsigned long long best[GS];
  __shared__ unsigned int remB[REMW];
  __shared__ int cnt_next;
  const int g = blockIdx.x;
  const int base = g * GS;
  const int t = threadIdx.x, nth = blockDim.x;
  const int lane = t & 63;

  for (int w = t; w < REMW; w += nth) {
    unsigned int bits = 0;
    int v0 = w * 32;
    if (v0 + 32 <= GS) {
      const unsigned int* p4 = (const unsigned int*)(remG + base + v0);
#pragma unroll
      for (int q = 0; q < 8; q++) {
        unsigned int x4 = p4[q];
        bits |= ((x4 & 1u) << (q * 4)) | (((x4 >> 8) & 1u) << (q * 4 + 1)) |
                (((x4 >> 16) & 1u) << (q * 4 + 2)) | (((x4 >> 24) & 1u) << (q * 4 + 3));
      }
    } else {
      for (int b = 0; b < 32; b++) {
        int v = v0 + b;
        if (v < GS) bits |= (remG[base + v] ? 1u : 0u) << b;
      }
    }
    remB[w] = bits;
  }
  for (int i = t; i < GS; i += nth) best[i] = 0ULL;
  __syncthreads();

  ulonglong2* bufs[2] = {recs0 + (size_t)g * CAP, recs1 + (size_t)g * CAP};
  int n = gcnts[g * GPAD];
  int cur = 0;
  int guard = 0;

  while (n > 0) {
    if (++guard > 100000) break;  // dormant watchdog (practical rounds ~30)
    // P1: live edges post priority (x4 batched loads for MLP)
    for (int i0 = 0; i0 < n; i0 += nth * 4) {
      ulonglong2 r[4];
      int have[4];
#pragma unroll
      for (int k = 0; k < 4; k++) {
        int i = i0 + t + k * nth;
        have[k] = i < n;
        if (have[k]) r[k] = bufs[cur][i];
      }
#pragma unroll
      for (int k = 0; k < 4; k++) {
        if (!have[k]) continue;
        int ls = (int)(r[k].y >> 32) - base, ld = (int)(r[k].y & 0xFFFFFFFFu) - base;
        if (((remB[ls >> 5] >> (ls & 31)) & 1u) && ((remB[ld >> 5] >> (ld & 31)) & 1u)) {
          atomicMax(&best[ls], r[k].x);
          if (ld != ls) atomicMax(&best[ld], r[k].x);
        }
      }
    }
    if (t == 0) cnt_next = 0;
    __syncthreads();
    // P2: winners commit; survivors compact
    for (int i0 = 0; i0 < n; i0 += nth * 4) {
      ulonglong2 r[4];
      int have[4];
#pragma unroll
      for (int k = 0; k < 4; k++) {
        int i = i0 + t + k * nth;
        have[k] = i < n;
        if (have[k]) r[k] = bufs[cur][i];
      }
#pragma unroll
      for (int k = 0; k < 4; k++) {
        int keep = 0;
        int ls = 0, ld = 0;
        if (have[k]) {
          ls = (int)(r[k].y >> 32) - base;
          ld = (int)(r[k].y & 0xFFFFFFFFu) - base;
          if (((remB[ls >> 5] >> (ls & 31)) & 1u) && ((remB[ld >> 5] >> (ld & 31)) & 1u)) {
            if (best[ls] == r[k].x && best[ld] == r[k].x) {
              int e = (int)(~(unsigned int)(r[k].x & 0xFFFFFFFFu));
              chosen[e] = 1;
              atomicAnd(&remB[ls >> 5], ~(1u << (ls & 31)));
              atomicAnd(&remB[ld >> 5], ~(1u << (ld & 31)));
            } else {
              keep = 1;
            }
          }
        }
        unsigned long long m = __ballot(keep);
        int tot = __popcll(m);
        int pre = __popcll(m & ((1ULL << lane) - 1ULL));
        int b0 = 0;
        if (lane == 0 && tot) b0 = atomicAdd(&cnt_next, tot);
        b0 = __shfl(b0, 0, 64);
        if (keep) bufs[cur ^ 1][b0 + pre] = r[k];
      }
    }
    __syncthreads();
    n = cnt_next;
    // P3: hybrid clear — survivor-driven for small rounds, full wipe otherwise
    if (n < 4096) {
      for (int i = t; i < n; i += nth) {
        ulonglong2 r = bufs[cur ^ 1][i];
        best[(int)(r.y >> 32) - base] = 0ULL;
        best[(int)(r.y & 0xFFFFFFFFu) - base] = 0ULL;
      }
    } else {
      for (int i = t; i < GS; i += nth) best[i] = 0ULL;
    }
    __syncthreads();
    cur ^= 1;
  }
}

// ---------- edge pool: post-matching ----------
__global__ void k_pool_edge(const int* __restrict__ src, const int* __restrict__ dst,
                            const unsigned char* __restrict__ chosen, const float* __restrict__ score,
                            unsigned char* __restrict__ nvout, float* __restrict__ scale,
                            int* __restrict__ partner, int* __restrict__ merged) {
  int e = blockIdx.x * blockDim.x + threadIdx.x;
  if (e >= EE) return;
  if (!chosen[e]) return;
  int s = src[e], d = dst[e];
  scale[s] = score[e];
  if (merged) merged[d] = s;
  if (s != d) {
    nvout[d] = 0;
    partner[s] = d;
  }
}

// fused: newx1 (never materialized) -> h2pre = newx1 @ W2
__global__ void k_newx_mm2(const float* __restrict__ h1, const int* __restrict__ partner,
                           const float* __restrict__ scale, const unsigned char* __restrict__ nvout,
                           const float* __restrict__ W2, float* __restrict__ h2pre) {
  int v = blockIdx.x * blockDim.x + threadIdx.x;
  if (v >= NN) return;
  float sc = scale[v];
  int ok = nvout[v];
  int p = partner[v];
  float nx[HH];
#pragma unroll
  for (int j = 0; j < HH; j++) {
    float a = h1[(size_t)v * HH + j];
    if (p >= 0) a += h1[(size_t)p * HH + j];
    nx[j] = ok ? a * sc : 0.f;
  }
#pragma unroll
  for (int c = 0; c < CC; c++) {
    float a = 0.f;
#pragma unroll
    for (int j = 0; j < HH; j++) a += nx[j] * W2[j * CC + c];
    h2pre[(size_t)v * CC + c] = a;
  }
}

// fused remap + dedup insert
__device__ __forceinline__ unsigned int ht_hash(unsigned long long key) {
  return (unsigned int)((key * 0x9E3779B97F4A7C15ULL) >> 44) & HT_MASK;
}

__global__ void k_remap_ins(const int* __restrict__ src, const int* __restrict__ dst,
                            const int* __restrict__ merged, int* __restrict__ ns,
                            int* __restrict__ nd, unsigned long long* __restrict__ htab) {
  int e = blockIdx.x * blockDim.x + threadIdx.x;
  if (e >= EE) return;
  int s = src[e], d = dst[e];
  int ms = merged[s], md = merged[d];
  int a = ms >= 0 ? ms : s;
  int b = md >= 0 ? md : d;
  ns[e] = a;
  nd[e] = b;
  unsigned long long key =
      (unsigned long long)((((unsigned int)a) << 16) | (unsigned int)b);
  unsigned long long val = (key << 32) | (unsigned int)e;
  unsigned int h = ht_hash(key);
  for (;;) {
    unsigned long long curv = htab[h];
    if (curv == ~0ULL) {
      unsigned long long prev = atomicCAS(&htab[h], ~0ULL, val);
      if (prev == ~0ULL) break;
      curv = prev;
    }
    if ((curv >> 32) == key) {
      if ((curv & 0xFFFFFFFFULL) > (unsigned long long)(unsigned int)e)
        atomicMin(&htab[h], val);
      break;
    }
    h = (h + 1) & HT_MASK;
  }
}

// fused dedup-mark + stage2 degree count (same edge domain; deg pre-zeroed by k_prep)
// Exonerated in R10 post-mortem (stage-1 slowdown predated this kernel; output correct).
__global__ void k_dedup_deg(const int* __restrict__ ns, const int* __restrict__ nd,
                            const unsigned long long* __restrict__ htab,
                            unsigned char* __restrict__ evout, float* __restrict__ deg,
                            unsigned char* __restrict__ hasloop) {
  int e = blockIdx.x * blockDim.x + threadIdx.x;
  if (e >= EE) return;
  unsigned long long key =
      (unsigned long long)((((unsigned int)ns[e]) << 16) | (unsigned int)nd[e]);
  unsigned int h = ht_hash(key);
  for (;;) {
    unsigned long long curv = htab[h];
    if ((curv >> 32) == key) {
      unsigned char ev = ((curv & 0xFFFFFFFFULL) == (unsigned long long)(unsigned int)e) ? 1 : 0;
      evout[e] = ev;
      if (ev) {
        int d = nd[e];
        atomicAdd(&deg[d], 1.0f);
        if (ns[e] == d) hasloop[d] = 1;
      }
      return;
    }
    h = (h + 1) & HT_MASK;
  }
}

// fused: newx2 (never materialized) -> graph mean-pool accumulate
__global__ void k_newx_pool(const float* __restrict__ h2, const int* __restrict__ partner,
                            const float* __restrict__ scale, const unsigned char* __restrict__ nv,
                            float* __restrict__ gsum, float* __restrict__ gcnt) {
  int v = blockIdx.x * blockDim.x + threadIdx.x;
  int lane = threadIdx.x & 63;
  int b = (v < NN ? v : NN - 1) / GS;
  int active = (v < NN) && nv[v];
  float cnt = active ? 1.f : 0.f;
  float val[CC];
  if (active) {
    float sc = scale[v];
    int p = partner[v];
    for (int j = 0; j < CC; j++) {
      float a = h2[(size_t)v * CC + j];
      if (p >= 0) a += h2[(size_t)p * CC + j];
      val[j] = a * sc;
    }
  } else {
    for (int j = 0; j < CC; j++) val[j] = 0.f;
  }
  int b0 = __shfl(b, 0, 64);
  unsigned long long same = __ballot(b == b0);
  if (same == ~0ULL) {
    for (int o = 32; o > 0; o >>= 1) {
      cnt += __shfl_down(cnt, o, 64);
      for (int j = 0; j < CC; j++) val[j] += __shfl_down(val[j], o, 64);
    }
    if (lane == 0 && cnt > 0.f) {
      atomicAdd(&gcnt[b0], cnt);
      for (int j = 0; j < CC; j++) atomicAdd(&gsum[b0 * CC + j], val[j]);
    }
  } else if (active) {
    atomicAdd(&gcnt[b], cnt);
    for (int j = 0; j < CC; j++) atomicAdd(&gsum[b * CC + j], val[j]);
  }
}

__global__ void k_logsm(const float* __restrict__ gsum, const float* __restrict__ gcnt,
                        float* __restrict__ out) {
  int t = threadIdx.x;
  if (t >= BB) return;
  float gr[CC];
  float c = gcnt[t];
  float m = -INFINITY;
  for (int j = 0; j < CC; j++) {
    gr[j] = gsum[t * CC + j] / c;
    m = fmaxf(m, gr[j]);
  }
  float s = 0.f;
  for (int j = 0; j < CC; j++) s += expf(gr[j] - m);
  float l = logf(s);
  for (int j = 0; j < CC; j++) out[t * CC + j] = gr[j] - m - l;
}

// ---------- host ----------
extern "C" void kernel_launch(void* const* d_in, const int* in_sizes, int n_in,
                              void* d_out, int out_size, void* d_ws, size_t ws_size,
                              hipStream_t stream) {
  const float* x = (const float*)d_in[0];
  const int* src = (const int*)d_in[1];
  const int* dst = (const int*)d_in[2];
  const float* W1 = (const float*)d_in[4];
  const float* b1 = (const float*)d_in[5];
  const float* W2 = (const float*)d_in[6];
  const float* b2 = (const float*)d_in[7];
  const float* Wp1 = (const float*)d_in[8];
  const float* bp1 = (const float*)d_in[9];
  const float* Wp2 = (const float*)d_in[10];
  const float* bp2 = (const float*)d_in[11];
  float* out = (float*)d_out;

  char* wsb = (char*)d_ws;
  size_t off = 0;
  auto A = [&](size_t bytes) -> char* {
    char* r = wsb + off;
    off = (off + bytes + 255) & ~(size_t)255;
    return r;
  };
  float* h1pre = (float*)A((size_t)NN * HH * 4);
  float* h1out = (float*)A((size_t)NN * HH * 4);
  float* deg = (float*)A((size_t)NN * 4);
  float* dinv = (float*)A((size_t)NN * 4);
  unsigned char* hasloop = (unsigned char*)A(NN);
  unsigned char* addloop = (unsigned char*)A(NN);
  float* raw = (float*)A((size_t)EE * 4);
  float* score = (float*)A((size_t)EE * 4);
  unsigned char* chosen = (unsigned char*)A(EE);
  unsigned char* nv1 = (unsigned char*)A(NN);
  unsigned char* nv2 = (unsigned char*)A(NN);
  float* scale = (float*)A((size_t)NN * 4);
  int* partner = (int*)A((size_t)NN * 4);
  int* merged = (int*)A((size_t)NN * 4);
  int* ns = (int*)A((size_t)EE * 4);
  int* nd = (int*)A((size_t)EE * 4);
  unsigned char* ev1 = (unsigned char*)A(EE);
  unsigned long long* htab = (unsigned long long*)A((size_t)HT_SIZE * 8);
  float* h2pre = (float*)A((size_t)NN * CC * 4);
  float* h2out = (float*)A((size_t)NN * CC * 4);
  unsigned long long* bestA = (unsigned long long*)A((size_t)NN * 8);
  unsigned long long* bestB = (unsigned long long*)A((size_t)NN * 8);
  unsigned char* remG = (unsigned char*)A(NN);
  ulonglong2* recs0 = (ulonglong2*)A((size_t)BB * CAP * 16);
  ulonglong2* recs1 = (ulonglong2*)A((size_t)BB * CAP * 16);
  int* gcntsA = (int*)A((size_t)BB * GPAD * 4);
  int* gcntsB = (int*)A((size_t)BB * GPAD * 4);
  float* gsum = (float*)A((size_t)BB * CC * 4);
  float* gcnt = (float*)A((size_t)BB * 4);
  int* rowstart = (int*)A((size_t)(NN + 1) * 4);
  int* fill = (int*)A((size_t)NN * 4);
  int* bsum = (int*)A((size_t)64 * 4);
  int* csrS = (int*)A((size_t)EE * 4);
  int* csrE = (int*)A((size_t)EE * 4);
  (void)ws_size; (void)n_in; (void)in_sizes; (void)out_size;

  const int GE = ngrid(EE), GN = ngrid(NN);
  const dim3 RG(32, BB);  // global-round grid: 32 blocks x 8 graphs

  // ===== stage 1: GCNConv(384->6) + ReLU =====
  hipMemsetAsync(htab, 0xFF, (size_t)HT_SIZE * 8, stream);
  hipLaunchKernelGGL(k_mm1, dim3((NN + 3) / 4), dim3(TPB), 0, stream, x, W1, h1pre);
  hipLaunchKernelGGL(k_prep, dim3(GN), dim3(TPB), 0, stream, deg, hasloop, gcntsA, gcntsB,
                     gsum, gcnt, (const unsigned char*)nullptr, nv1, scale, merged, partner, bestA, bestB, remG);
  hipLaunchKernelGGL(k_deg, dim3(GE), dim3(TPB), 0, stream, src, dst, (const unsigned char*)nullptr, deg, hasloop);
  hipLaunchKernelGGL(k_scan1, dim3(NBLK), dim3(SCAN_B), 0, stream, deg, rowstart, bsum);
  hipLaunchKernelGGL(k_scan3, dim3(GN), dim3(TPB), 0, stream, rowstart, bsum, fill, deg, hasloop,
                     (const unsigned char*)nullptr, dinv, addloop);
  hipLaunchKernelGGL(k_scatter, dim3(GE), dim3(TPB), 0, stream, src, dst, (const unsigned char*)nullptr, fill, csrS, csrE);
  hipLaunchKernelGGL(k_agg_fin<HH>, dim3(GN), dim3(TPB), 0, stream, rowstart, csrS, dinv, addloop, h1pre, b1, h1out, 1);

  // ===== edge pool 1 =====
  hipLaunchKernelGGL(k_raw, dim3(GE), dim3(TPB), 0, stream, h1out, src, dst, (const unsigned char*)nullptr, Wp1, bp1, raw, chosen, HH);
  hipLaunchKernelGGL(k_smscore, dim3(GN), dim3(TPB), 0, stream, rowstart, csrS, csrE, raw, remG, score, bestA);
  hipLaunchKernelGGL(k_r1sel, dim3(GE), dim3(TPB), 0, stream, src, dst, score, (const unsigned char*)nullptr, remG, bestA, bestB, chosen, recs0, gcntsA);
  // global rounds 2-6 (split post/sel — R7 lesson: fusing stalls commits)
  hipLaunchKernelGGL(k_gpost, RG, dim3(TPB), 0, stream, recs0, gcntsA, remG, bestB, gcntsB);
  hipLaunchKernelGGL(k_gsel, RG, dim3(TPB), 0, stream, recs0, gcntsA, remG, bestB, bestA, chosen, recs1, gcntsB);
  hipLaunchKernelGGL(k_gpost, RG, dim3(TPB), 0, stream, recs1, gcntsB, remG, bestA, gcntsA);
  hipLaunchKernelGGL(k_gsel, RG, dim3(TPB), 0, stream, recs1, gcntsB, remG, bestA, bestB, chosen, recs0, gcntsA);
  hipLaunchKernelGGL(k_gpost, RG, dim3(TPB), 0, stream, recs0, gcntsA, remG, bestB, gcntsB);
  hipLaunchKernelGGL(k_gsel, RG, dim3(TPB), 0, stream, recs0, gcntsA, remG, bestB, bestA, chosen, recs1, gcntsB);
  hipLaunchKernelGGL(k_gpost, RG, dim3(TPB), 0, stream, recs1, gcntsB, remG, bestA, gcntsA);
  hipLaunchKernelGGL(k_gsel, RG, dim3(TPB), 0, stream, recs1, gcntsB, remG, bestA, bestB, chosen, recs0, gcntsA);
  hipLaunchKernelGGL(k_gpost, RG, dim3(TPB), 0, stream, recs0, gcntsA, remG, bestB, gcntsB);
  hipLaunchKernelGGL(k_gsel, RG, dim3(TPB), 0, stream, recs0, gcntsA, remG, bestB, bestA, chosen, recs1, gcntsB);
  // LDS tail
  hipLaunchKernelGGL(k_match_g, dim3(BB), dim3(1024), 0, stream, recs1, recs0, gcntsB, remG, chosen);
  hipLaunchKernelGGL(k_pool_edge, dim3(GE), dim3(TPB), 0, stream, src, dst, chosen, score, nv1, scale, partner, merged);
  hipLaunchKernelGGL(k_newx_mm2, dim3(GN), dim3(TPB), 0, stream, h1out, partner, scale, nv1, W2, h2pre);
  hipLaunchKernelGGL(k_remap_ins, dim3(GE), dim3(TPB), 0, stream, src, dst, merged, ns, nd, htab);

  // ===== stage 2: GCNConv(6->10) =====
  hipLaunchKernelGGL(k_prep, dim3(GN), dim3(TPB), 0, stream, deg, hasloop, gcntsA, gcntsB,
                     gsum, gcnt, (const unsigned char*)nv1, nv2, scale, (int*)nullptr, partner, bestA, bestB, remG);
  hipLaunchKernelGGL(k_dedup_deg, dim3(GE), dim3(TPB), 0, stream, ns, nd, htab, ev1, deg, hasloop);
  hipLaunchKernelGGL(k_scan1, dim3(NBLK), dim3(SCAN_B), 0, stream, deg, rowstart, bsum);
  hipLaunchKernelGGL(k_scan3, dim3(GN), dim3(TPB), 0, stream, rowstart, bsum, fill, deg, hasloop,
                     (const unsigned char*)nv1, dinv, addloop);
  hipLaunchKernelGGL(k_scatter, dim3(GE), dim3(TPB), 0, stream, ns, nd, (const unsigned char*)ev1, fill, csrS, csrE);
  hipLaunchKernelGGL(k_agg_fin<CC>, dim3(GN), dim3(TPB), 0, stream, rowstart, csrS, dinv, addloop, h2pre, b2, h2out, 0);

  // ===== edge pool 2 =====
  hipLaunchKernelGGL(k_raw, dim3(GE), dim3(TPB), 0, stream, h2out, ns, nd, (const unsigned char*)ev1, Wp2, bp2, raw, chosen, CC);
  hipLaunchKernelGGL(k_smscore, dim3(GN), dim3(TPB), 0, stream, rowstart, csrS, csrE, raw, remG, score, bestA);
  hipLaunchKernelGGL(k_r1sel, dim3(GE), dim3(TPB), 0, stream, ns, nd, score, (const unsigned char*)ev1, remG, bestA, bestB, chosen, recs0, gcntsA);
  hipLaunchKernelGGL(k_gpost, RG, dim3(TPB), 0, stream, recs0, gcntsA, remG, bestB, gcntsB);
  hipLaunchKernelGGL(k_gsel, RG, dim3(TPB), 0, stream, recs0, gcntsA, remG, bestB, bestA, chosen, recs1, gcntsB);
  hipLaunchKernelGGL(k_gpost, RG, dim3(TPB), 0, stream, recs1, gcntsB, remG, bestA, gcntsA);
  hipLaunchKernelGGL(k_gsel, RG, dim3(TPB), 0, stream, recs1, gcntsB, remG, bestA, bestB, chosen, recs0, gcntsA);
  hipLaunchKernelGGL(k_gpost, RG, dim3(TPB), 0, stream, recs0, gcntsA, remG, bestB, gcntsB);
  hipLaunchKernelGGL(k_gsel, RG, dim3(TPB), 0, stream, recs0, gcntsA, remG, bestB, bestA, chosen, recs1, gcntsB);
  hipLaunchKernelGGL(k_gpost, RG, dim3(TPB), 0, stream, recs1, gcntsB, remG, bestA, gcntsA);
  hipLaunchKernelGGL(k_gsel, RG, dim3(TPB), 0, stream, recs1, gcntsB, remG, bestA, bestB, chosen, recs0, gcntsA);
  hipLaunchKernelGGL(k_gpost, RG, dim3(TPB), 0, stream, recs0, gcntsA, remG, bestB, gcntsB);
  hipLaunchKernelGGL(k_gsel, RG, dim3(TPB), 0, stream, recs0, gcntsA, remG, bestB, bestA, chosen, recs1, gcntsB);
  hipLaunchKernelGGL(k_match_g, dim3(BB), dim3(1024), 0, stream, recs1, recs0, gcntsB, remG, chosen);
  hipLaunchKernelGGL(k_pool_edge, dim3(GE), dim3(TPB), 0, stream, ns, nd, chosen, score, nv2, scale, partner, (int*)nullptr);

  // ===== readout =====
  hipLaunchKernelGGL(k_newx_pool, dim3(GN), dim3(TPB), 0, stream, h2out, partner, scale, nv2, gsum, gcnt);
  hipLaunchKernelGGL(k_logsm, dim3(1), dim3(64), 0, stream, gsum, gcnt, out);
}

// Round 12
// 1329.987 us; speedup vs baseline: 99.1997x; 1.0561x over previous
//
#include <hip/hip_runtime.h>
#include <math.h>

#define NN 60000
#define BB 8
#define GS 7500   // nodes per graph
#define FF 384
#define EE 600000
#define HH 6
#define CC 10
#define HT_BITS 20
#define HT_SIZE (1u << HT_BITS)
#define HT_MASK (HT_SIZE - 1u)
#define TPB 256
#define CAP 80000  // per-graph edge capacity
#define REMW ((GS + 31) / 32)
#define GPAD 32    // counter padding: one per 128B (R3 lesson)
#define SCAN_B 1024
#define NBLK ((NN + SCAN_B - 1) / SCAN_B)  // 59
static_assert(NBLK <= 64, "scan3 wave-scan assumes <=64 blocks");
static_assert((HH % 2) == 0 && (CC % 2) == 0, "float2 paths assume even fd");

static inline int ngrid(int n) { return (n + TPB - 1) / TPB; }

// ---------- helpers ----------
__device__ __forceinline__ unsigned long long mkprio(float sc, int e) {
  return (((unsigned long long)__float_as_uint(sc)) << 32) |
         (unsigned int)(~(unsigned int)e);
}

// ---------- stage 1 matmul: h1pre = x @ W1 ----------
__global__ void k_mm1(const float* __restrict__ x, const float* __restrict__ W,
                      float* __restrict__ out) {
  __shared__ float Ws[FF * HH];
  for (int i = threadIdx.x; i < FF * HH; i += blockDim.x) Ws[i] = W[i];
  __syncthreads();
  int wave = threadIdx.x >> 6, lane = threadIdx.x & 63;
  int node = blockIdx.x * 4 + wave;
  if (node >= NN) return;
  const float* xr = x + (size_t)node * FF;
  float acc[HH] = {0.f, 0.f, 0.f, 0.f, 0.f, 0.f};
  for (int k = lane; k < FF; k += 64) {
    float xv = xr[k];
#pragma unroll
    for (int j = 0; j < HH; j++) acc[j] += xv * Ws[k * HH + j];
  }
#pragma unroll
  for (int j = 0; j < HH; j++) {
#pragma unroll
    for (int o = 32; o > 0; o >>= 1) acc[j] += __shfl_down(acc[j], o, 64);
  }
  if (lane == 0) {
#pragma unroll
    for (int j = 0; j < HH; j++) out[(size_t)node * HH + j] = acc[j];
  }
}

// ---------- fused per-stage init (stage 1 only; stage 2 fused into k_newx_prep) ----------
__global__ void k_prep(float* __restrict__ deg, unsigned char* __restrict__ hasloop,
                       int* __restrict__ gcntsA,
                       int* __restrict__ gcntsB, float* __restrict__ gsum,
                       float* __restrict__ gcnt, const unsigned char* __restrict__ nvin,
                       unsigned char* __restrict__ nvout, float* __restrict__ scale,
                       int* __restrict__ merged, int* __restrict__ partner,
                       unsigned long long* __restrict__ bestA,
                       unsigned long long* __restrict__ bestB,
                       unsigned char* __restrict__ remG) {
  int v = blockIdx.x * blockDim.x + threadIdx.x;
  if (v >= NN) return;
  deg[v] = 0.f;
  hasloop[v] = 0;
  unsigned char nvv = nvin ? nvin[v] : 1;
  nvout[v] = nvv;
  remG[v] = nvv;
  bestA[v] = 0ULL;
  bestB[v] = 0ULL;
  scale[v] = 1.0f;
  if (merged) merged[v] = -1;
  partner[v] = -1;
  if (v < BB * GPAD) { gcntsA[v] = 0; gcntsB[v] = 0; }
  if (v < BB * CC) gsum[v] = 0.f;
  if (v < BB) gcnt[v] = 0.f;
}

// ---------- generic GCN conv pieces ----------
__global__ void k_deg(const int* __restrict__ src, const int* __restrict__ dst,
                      const unsigned char* __restrict__ ev, float* __restrict__ deg,
                      unsigned char* __restrict__ hasloop) {
  int e = blockIdx.x * blockDim.x + threadIdx.x;
  if (e >= EE) return;
  if (ev && !ev[e]) return;
  int d = dst[e];
  atomicAdd(&deg[d], 1.0f);
  if (src[e] == d) hasloop[d] = 1;
}

// ---------- CSR build: scan of deg -> rowstart, then scatter ----------
__global__ __launch_bounds__(1024) void k_scan1(const float* __restrict__ deg,
                                                int* __restrict__ rowstart,
                                                int* __restrict__ bsum) {
  __shared__ int tmp[SCAN_B];
  int t = threadIdx.x;
  int i = blockIdx.x * SCAN_B + t;
  int v = (i < NN) ? (int)deg[i] : 0;
  tmp[t] = v;
  __syncthreads();
  for (int o = 1; o < SCAN_B; o <<= 1) {
    int y = (t >= o) ? tmp[t - o] : 0;
    __syncthreads();
    tmp[t] += y;
    __syncthreads();
  }
  if (i < NN) rowstart[i] = tmp[t] - v;  // exclusive within block
  if (t == SCAN_B - 1) bsum[blockIdx.x] = tmp[t];
}

// scan fixup (each block wave-scans the 59 block sums itself) + fused dinv/addloop
__global__ void k_scan3(int* __restrict__ rowstart, const int* __restrict__ bsum,
                        int* __restrict__ fill, const float* __restrict__ deg,
                        const unsigned char* __restrict__ hasloop,
                        const unsigned char* __restrict__ nv, float* __restrict__ dinv,
                        unsigned char* __restrict__ addloop) {
  __shared__ int offs[64];
  __shared__ int total;
  int t = threadIdx.x;
  if (t < 64) {
    int v = (t < NBLK) ? bsum[t] : 0;
    int x = v;
#pragma unroll
    for (int o = 1; o < 64; o <<= 1) {
      int y = __shfl_up(x, o, 64);
      if (t >= o) x += y;
    }
    offs[t] = x - v;          // exclusive block offset
    if (t == 63) total = x;   // grand total
  }
  __syncthreads();
  int i = blockIdx.x * blockDim.x + t;
  if (i >= NN) return;
  int r = rowstart[i] + offs[i >> 10];  // SCAN_B == 1024
  rowstart[i] = r;
  fill[i] = r;
  if (i == NN - 1) rowstart[NN] = total;
  int nvv = nv ? (int)nv[i] : 1;
  unsigned char al = (nvv && !hasloop[i]) ? 1 : 0;
  float d = deg[i] + (float)al;
  dinv[i] = d > 0.f ? 1.0f / sqrtf(fmaxf(d, 1e-12f)) : 0.f;
  addloop[i] = al;
}

__global__ void k_scatter(const int* __restrict__ src, const int* __restrict__ dst,
                          const unsigned char* __restrict__ ev, int* __restrict__ fill,
                          int* __restrict__ csrS, int* __restrict__ csrE) {
  int e = blockIdx.x * blockDim.x + threadIdx.x;
  if (e >= EE) return;
  if (ev && !ev[e]) return;
  int d = dst[e];
  int p = atomicAdd(&fill[d], 1);
  csrS[p] = src[e];
  csrE[p] = e;
}

// fused gather aggregation + finalize + per-node src-score a[v] = out_row . Wp[0:FD]
// (EdgePool raw score is separable: raw[e] = a[src] + (h[dst].Wp[fd:]+bp); the dst
// term is constant within each dst softmax group and cancels -> only a[] needed.)
template <int FD>
__global__ void k_agg_fin(const int* __restrict__ rowstart, const int* __restrict__ csrS,
                          const float* __restrict__ dinv, const unsigned char* __restrict__ addloop,
                          const float* __restrict__ h, const float* __restrict__ b,
                          const float* __restrict__ Wp, float* __restrict__ aout,
                          float* __restrict__ out, int relu) {
  int v = blockIdx.x * blockDim.x + threadIdx.x;
  if (v >= NN) return;
  int b0 = rowstart[v], b1 = rowstart[v + 1];
  float acc[FD];
#pragma unroll
  for (int j = 0; j < FD; j++) acc[j] = 0.f;
  float dv = dinv[v];
  for (int i = b0; i < b1; i++) {
    int s = csrS[i];
    float c = dinv[s] * dv;  // per-edge coef, matches reference factoring
    const float2* hr2 = (const float2*)(h + (size_t)s * FD);
#pragma unroll
    for (int j = 0; j < FD / 2; j++) {
      float2 hv = hr2[j];
      acc[2 * j] += hv.x * c;
      acc[2 * j + 1] += hv.y * c;
    }
  }
  float cl = addloop[v] ? dv * dv : 0.f;
  const float* hv = h + (size_t)v * FD;
  float av = 0.f;
#pragma unroll
  for (int j = 0; j < FD; j++) {
    float o = acc[j] + cl * hv[j] + b[j];
    if (relu) o = fmaxf(o, 0.f);
    out[(size_t)v * FD + j] = o;
    av += o * Wp[j];
  }
  aout[v] = av;
}

// fused softmax stats + score + bestA posting, a[]-factorized (dst term cancels).
__global__ void k_smscore(const int* __restrict__ rowstart, const int* __restrict__ csrS,
                          const int* __restrict__ csrE, const float* __restrict__ a,
                          const unsigned char* __restrict__ remG, float* __restrict__ score,
                          unsigned long long* __restrict__ bestA) {
  int v = blockIdx.x * blockDim.x + threadIdx.x;
  if (v >= NN) return;
  int b0 = rowstart[v], b1 = rowstart[v + 1];
  if (b0 == b1) return;
  float ma = -INFINITY;
  for (int i = b0; i < b1; i++) ma = fmaxf(ma, a[csrS[i]]);
  float s = 0.f;
  for (int i = b0; i < b1; i++) s += expf(a[csrS[i]] - ma);
  if (!remG[v]) return;
  float sd = s > 0.f ? s : 1.0f;
  unsigned long long lb = 0ULL;
  for (int i = b0; i < b1; i++) {
    int sv = csrS[i];
    if (!remG[sv]) continue;
    int e = csrE[i];
    float sc = expf(a[sv] - ma) / sd + 0.5f;
    score[e] = sc;
    unsigned long long p = mkprio(sc, e);
    if (p > lb) lb = p;
    if (sv != v && p > bestA[sv]) atomicMax(&bestA[sv], p);
  }
  if (lb > bestA[v]) atomicMax(&bestA[v], lb);
}

// ---------- round 1 select + compact; survivors zero bestB; also zeroes chosen[] ----------
__global__ void k_r1sel(const int* __restrict__ src, const int* __restrict__ dst,
                        const float* __restrict__ score, const unsigned char* __restrict__ ev,
                        unsigned char* __restrict__ remG,
                        const unsigned long long* __restrict__ bestA,
                        unsigned long long* __restrict__ bestB,
                        unsigned char* __restrict__ chosen, ulonglong2* __restrict__ recs,
                        int* __restrict__ gcnts) {
  __shared__ int wcnt[TPB / 64][BB];
  __shared__ int bbase[BB];
  int e = blockIdx.x * blockDim.x + threadIdx.x;
  int w = threadIdx.x >> 6, lane = threadIdx.x & 63;
  int keep = 0, s = 0, d = 0, g = 0;
  unsigned long long p = 0;
  if (e < EE) chosen[e] = 0;  // zero-then-maybe-set, same thread (replaces k_raw's zeroing)
  if (e < EE && (!ev || ev[e])) {
    s = src[e];
    d = dst[e];
    g = s / GS;
    if (remG[s] && remG[d]) {
      p = mkprio(score[e], e);
      if (bestA[s] == p && bestA[d] == p) {
        chosen[e] = 1;
        remG[s] = 0;
        remG[d] = 0;
      } else {
        keep = 1;
        bestB[s] = 0ULL;  // benign write race; next round's buffer
        bestB[d] = 0ULL;
      }
    }
  }
  int myrank = 0;
#pragma unroll
  for (int gg = 0; gg < BB; gg++) {
    unsigned long long m = __ballot(keep && g == gg);
    if (keep && g == gg) myrank = __popcll(m & ((1ULL << lane) - 1ULL));
    if (lane == 0) wcnt[w][gg] = __popcll(m);
  }
  __syncthreads();
  if (threadIdx.x < BB) {
    int gg = threadIdx.x, tot = 0;
#pragma unroll
    for (int ww = 0; ww < TPB / 64; ww++) {
      int c = wcnt[ww][gg];
      wcnt[ww][gg] = tot;
      tot += c;
    }
    bbase[gg] = tot ? atomicAdd(&gcnts[gg * GPAD], tot) : 0;
  }
  __syncthreads();
  if (keep)
    recs[(size_t)g * CAP + bbase[g] + wcnt[w][g] + myrank] =
        make_ulonglong2(p, (((unsigned long long)(unsigned int)s) << 32) | (unsigned int)d);
}

// ---------- generic global round (full GPU) over compacted lists ----------
// R7 lesson: do NOT fuse post into the select kernel. R9 lesson: do NOT use
// cooperative grid.sync (forces L2 flush on gfx950 -> 100MB refetch/round).
__global__ void k_gpost(const ulonglong2* __restrict__ recs, const int* __restrict__ gcnts,
                        const unsigned char* __restrict__ remG,
                        unsigned long long* __restrict__ bestC, int* __restrict__ gcntsOut) {
  int g = blockIdx.y;
  if (blockIdx.x == 0 && threadIdx.x == 0) gcntsOut[g * GPAD] = 0;
  int n = gcnts[g * GPAD];
  const ulonglong2* lst = recs + (size_t)g * CAP;
  int stride = gridDim.x * blockDim.x;
  for (int i = blockIdx.x * blockDim.x + threadIdx.x; i < n; i += stride) {
    ulonglong2 r = lst[i];
    int s = (int)(r.y >> 32), d = (int)(r.y & 0xFFFFFFFFu);
    if (remG[s] && remG[d]) {
      if (r.x > bestC[s]) atomicMax(&bestC[s], r.x);
      if (d != s && r.x > bestC[d]) atomicMax(&bestC[d], r.x);
    }
  }
}

// sel: winners commit; survivors -> out list + zero bestN (next buffer)
__global__ void k_gsel(const ulonglong2* __restrict__ recsIn, const int* __restrict__ gcntsIn,
                       unsigned char* __restrict__ remG,
                       const unsigned long long* __restrict__ bestC,
                       unsigned long long* __restrict__ bestN,
                       unsigned char* __restrict__ chosen, ulonglong2* __restrict__ recsOut,
                       int* __restrict__ gcntsOut) {
  int g = blockIdx.y;
  int n = gcntsIn[g * GPAD];
  const ulonglong2* lst = recsIn + (size_t)g * CAP;
  ulonglong2* outl = recsOut + (size_t)g * CAP;
  int lane = threadIdx.x & 63;
  int stride = gridDim.x * blockDim.x;
  for (int i = blockIdx.x * blockDim.x + threadIdx.x; i - lane < n; i += stride) {
    int keep = 0;
    ulonglong2 r;
    if (i < n) {
      r = lst[i];
      int s = (int)(r.y >> 32), d = (int)(r.y & 0xFFFFFFFFu);
      if (remG[s] && remG[d]) {
        if (bestC[s] == r.x && bestC[d] == r.x) {
          int e = (int)(~(unsigned int)(r.x & 0xFFFFFFFFu));
          chosen[e] = 1;
          remG[s] = 0;
          remG[d] = 0;
        } else {
          keep = 1;
          bestN[s] = 0ULL;
          bestN[d] = 0ULL;
        }
      }
    }
    unsigned long long m = __ballot(keep);
    int tot = __popcll(m);
    int pre = __popcll(m & ((1ULL << lane) - 1ULL));
    int b0 = 0;
    if (lane == 0 && tot) b0 = atomicAdd(&gcntsOut[g * GPAD], tot);
    b0 = __shfl(b0, 0, 64);
    if (keep) outl[b0 + pre] = r;
  }
}

// ---------- matching tail: per-graph LDS fixpoint (R8-verified form, verbatim) ----------
// R2/R3 + R10 lesson: do NOT register-cache records across the P1/P2/P3 barriers
// (2/2 attempts degenerated to O(1)-commit rounds, ~1000x slower). Always re-read
// the list per phase. P3's clear doubles as the cnt_next handoff barrier.
__global__ __launch_bounds__(1024) void k_match_g(ulonglong2* __restrict__ recs0,
                                                  ulonglong2* __restrict__ recs1,
                                                  const int* __restrict__ gcnts,
                                                  const unsigned char* __restrict__ remG,
                                                  unsigned char* __restrict__ chosen) {
  __shared__ unsigned long long best[GS];
  __shared__ unsigned int remB[REMW];
  __shared__ int cnt_next;
  const int g = blockIdx.x;
  const int base = g * GS;
  const int t = threadIdx.x, nth = blockDim.x;
  const int lane = t & 63;

  for (int w = t; w < REMW; w += nth) {
    unsigned int bits = 0;
    int v0 = w * 32;
    if (v0 + 32 <= GS) {
      const unsigned int* p4 = (const unsigned int*)(remG + base + v0);
#pragma unroll
      for (int q = 0; q < 8; q++) {
        unsigned int x4 = p4[q];
        bits |= ((x4 & 1u) << (q * 4)) | (((x4 >> 8) & 1u) << (q * 4 + 1)) |
                (((x4 >> 16) & 1u) << (q * 4 + 2)) | (((x4 >> 24) & 1u) << (q * 4 + 3));
      }
    } else {
      for (int b = 0; b < 32; b++) {
        int v = v0 + b;
        if (v < GS) bits |= (remG[base + v] ? 1u : 0u) << b;
      }
    }
    remB[w] = bits;
  }
  for (int i = t; i < GS; i += nth) best[i] = 0ULL;
  __syncthreads();

  ulonglong2* bufs[2] = {recs0 + (size_t)g * CAP, recs1 + (size_t)g * CAP};
  int n = gcnts[g * GPAD];
  int cur = 0;
  int guard = 0;

  while (n > 0) {
    if (++guard > 100000) break;  // dormant watchdog (practical rounds ~30)
    // P1: live edges post priority (x4 batched loads for MLP)
    for (int i0 = 0; i0 < n; i0 += nth * 4) {
      ulonglong2 r[4];
      int have[4];
#pragma unroll
      for (int k = 0; k < 4; k++) {
        int i = i0 + t + k * nth;
        have[k] = i < n;
        if (have[k]) r[k] = bufs[cur][i];
      }
#pragma unroll
      for (int k = 0; k < 4; k++) {
        if (!have[k]) continue;
        int ls = (int)(r[k].y >> 32) - base, ld = (int)(r[k].y & 0xFFFFFFFFu) - base;
        if (((remB[ls >> 5] >> (ls & 31)) & 1u) && ((remB[ld >> 5] >> (ld & 31)) & 1u)) {
          atomicMax(&best[ls], r[k].x);
          if (ld != ls) atomicMax(&best[ld], r[k].x);
        }
      }
    }
    if (t == 0) cnt_next = 0;
    __syncthreads();
    // P2: winners commit; survivors compact
    for (int i0 = 0; i0 < n; i0 += nth * 4) {
      ulonglong2 r[4];
      int have[4];
#pragma unroll
      for (int k = 0; k < 4; k++) {
        int i = i0 + t + k * nth;
        have[k] = i < n;
        if (have[k]) r[k] = bufs[cur][i];
      }
#pragma unroll
      for (int k = 0; k < 4; k++) {
        int keep = 0;
        int ls = 0, ld = 0;
        if (have[k]) {
          ls = (int)(r[k].y >> 32) - base;
          ld = (int)(r[k].y & 0xFFFFFFFFu) - base;
          if (((remB[ls >> 5] >> (ls & 31)) & 1u) && ((remB[ld >> 5] >> (ld & 31)) & 1u)) {
            if (best[ls] == r[k].x && best[ld] == r[k].x) {
              int e = (int)(~(unsigned int)(r[k].x & 0xFFFFFFFFu));
              chosen[e] = 1;
              atomicAnd(&remB[ls >> 5], ~(1u << (ls & 31)));
              atomicAnd(&remB[ld >> 5], ~(1u << (ld & 31)));
            } else {
              keep = 1;
            }
          }
        }
        unsigned long long m = __ballot(keep);
        int tot = __popcll(m);
        int pre = __popcll(m & ((1ULL << lane) - 1ULL));
        int b0 = 0;
        if (lane == 0 && tot) b0 = atomicAdd(&cnt_next, tot);
        b0 = __shfl(b0, 0, 64);
        if (keep) bufs[cur ^ 1][b0 + pre] = r[k];
      }
    }
    __syncthreads();
    n = cnt_next;
    // P3: hybrid clear — survivor-driven for small rounds, full wipe otherwise
    if (n < 4096) {
      for (int i = t; i < n; i += nth) {
        ulonglong2 r = bufs[cur ^ 1][i];
        best[(int)(r.y >> 32) - base] = 0ULL;
        best[(int)(r.y & 0xFFFFFFFFu) - base] = 0ULL;
      }
    } else {
      for (int i = t; i < GS; i += nth) best[i] = 0ULL;
    }
    __syncthreads();
    cur ^= 1;
  }
}

// ---------- edge pool: post-matching ----------
__global__ void k_pool_edge(const int* __restrict__ src, const int* __restrict__ dst,
                            const unsigned char* __restrict__ chosen, const float* __restrict__ score,
                            unsigned char* __restrict__ nvout, float* __restrict__ scale,
                            int* __restrict__ partner, int* __restrict__ merged) {
  int e = blockIdx.x * blockDim.x + threadIdx.x;
  if (e >= EE) return;
  if (!chosen[e]) return;
  int s = src[e], d = dst[e];
  scale[s] = score[e];
  if (merged) merged[d] = s;
  if (s != d) {
    nvout[d] = 0;
    partner[s] = d;
  }
}

// fused: newx1 -> h2pre = newx1 @ W2, PLUS stage-2 per-node init (was k_prep).
// Per-thread order: read stage-1 partner/scale/nv1 and compute mm2 FIRST, then
// reset the per-node matching state for stage 2 (program order, no cross-thread
// hazards; merged[] is untouched, k_remap_ins still reads it afterwards).
__global__ void k_newx_prep(const float* __restrict__ h1, const float* __restrict__ W2,
                            float* __restrict__ h2pre,
                            float* __restrict__ deg, unsigned char* __restrict__ hasloop,
                            int* __restrict__ gcntsA, int* __restrict__ gcntsB,
                            float* __restrict__ gsum, float* __restrict__ gcnt,
                            const unsigned char* __restrict__ nv1,
                            unsigned char* __restrict__ nv2, float* __restrict__ scale,
                            int* __restrict__ partner,
                            unsigned long long* __restrict__ bestA,
                            unsigned long long* __restrict__ bestB,
                            unsigned char* __restrict__ remG) {
  int v = blockIdx.x * blockDim.x + threadIdx.x;
  if (v >= NN) return;
  // --- newx_mm2 (stage-1 state reads) ---
  float sc = scale[v];
  unsigned char nvv = nv1[v];
  int ok = nvv;
  int p = partner[v];
  float nx[HH];
#pragma unroll
  for (int j = 0; j < HH; j++) {
    float a = h1[(size_t)v * HH + j];
    if (p >= 0) a += h1[(size_t)p * HH + j];
    nx[j] = ok ? a * sc : 0.f;
  }
#pragma unroll
  for (int c = 0; c < CC; c++) {
    float a = 0.f;
#pragma unroll
    for (int j = 0; j < HH; j++) a += nx[j] * W2[j * CC + c];
    h2pre[(size_t)v * CC + c] = a;
  }
  // --- stage-2 prep (writes after reads) ---
  deg[v] = 0.f;
  hasloop[v] = 0;
  nv2[v] = nvv;
  remG[v] = nvv;
  bestA[v] = 0ULL;
  bestB[v] = 0ULL;
  scale[v] = 1.0f;
  partner[v] = -1;
  if (v < BB * GPAD) { gcntsA[v] = 0; gcntsB[v] = 0; }
  if (v < BB * CC) gsum[v] = 0.f;
  if (v < BB) gcnt[v] = 0.f;
}

// fused remap + dedup insert
__device__ __forceinline__ unsigned int ht_hash(unsigned long long key) {
  return (unsigned int)((key * 0x9E3779B97F4A7C15ULL) >> 44) & HT_MASK;
}

__global__ void k_remap_ins(const int* __restrict__ src, const int* __restrict__ dst,
                            const int* __restrict__ merged, int* __restrict__ ns,
                            int* __restrict__ nd, unsigned long long* __restrict__ htab) {
  int e = blockIdx.x * blockDim.x + threadIdx.x;
  if (e >= EE) return;
  int s = src[e], d = dst[e];
  int ms = merged[s], md = merged[d];
  int a = ms >= 0 ? ms : s;
  int b = md >= 0 ? md : d;
  ns[e] = a;
  nd[e] = b;
  unsigned long long key =
      (unsigned long long)((((unsigned int)a) << 16) | (unsigned int)b);
  unsigned long long val = (key << 32) | (unsigned int)e;
  unsigned int h = ht_hash(key);
  for (;;) {
    unsigned long long curv = htab[h];
    if (curv == ~0ULL) {
      unsigned long long prev = atomicCAS(&htab[h], ~0ULL, val);
      if (prev == ~0ULL) break;
      curv = prev;
    }
    if ((curv >> 32) == key) {
      if ((curv & 0xFFFFFFFFULL) > (unsigned long long)(unsigned int)e)
        atomicMin(&htab[h], val);
      break;
    }
    h = (h + 1) & HT_MASK;
  }
}

// fused dedup-mark + stage2 degree count (same edge domain; deg pre-zeroed by k_newx_prep)
__global__ void k_dedup_deg(const int* __restrict__ ns, const int* __restrict__ nd,
                            const unsigned long long* __restrict__ htab,
                            unsigned char* __restrict__ evout, float* __restrict__ deg,
                            unsigned char* __restrict__ hasloop) {
  int e = blockIdx.x * blockDim.x + threadIdx.x;
  if (e >= EE) return;
  unsigned long long key =
      (unsigned long long)((((unsigned int)ns[e]) << 16) | (unsigned int)nd[e]);
  unsigned int h = ht_hash(key);
  for (;;) {
    unsigned long long curv = htab[h];
    if ((curv >> 32) == key) {
      unsigned char ev = ((curv & 0xFFFFFFFFULL) == (unsigned long long)(unsigned int)e) ? 1 : 0;
      evout[e] = ev;
      if (ev) {
        int d = nd[e];
        atomicAdd(&deg[d], 1.0f);
        if (ns[e] == d) hasloop[d] = 1;
      }
      return;
    }
    h = (h + 1) & HT_MASK;
  }
}

// fused: newx2 (never materialized) -> graph mean-pool accumulate
__global__ void k_newx_pool(const float* __restrict__ h2, const int* __restrict__ partner,
                            const float* __restrict__ scale, const unsigned char* __restrict__ nv,
                            float* __restrict__ gsum, float* __restrict__ gcnt) {
  int v = blockIdx.x * blockDim.x + threadIdx.x;
  int lane = threadIdx.x & 63;
  int b = (v < NN ? v : NN - 1) / GS;
  int active = (v < NN) && nv[v];
  float cnt = active ? 1.f : 0.f;
  float val[CC];
  if (active) {
    float sc = scale[v];
    int p = partner[v];
    for (int j = 0; j < CC; j++) {
      float a = h2[(size_t)v * CC + j];
      if (p >= 0) a += h2[(size_t)p * CC + j];
      val[j] = a * sc;
    }
  } else {
    for (int j = 0; j < CC; j++) val[j] = 0.f;
  }
  int b0 = __shfl(b, 0, 64);
  unsigned long long same = __ballot(b == b0);
  if (same == ~0ULL) {
    for (int o = 32; o > 0; o >>= 1) {
      cnt += __shfl_down(cnt, o, 64);
      for (int j = 0; j < CC; j++) val[j] += __shfl_down(val[j], o, 64);
    }
    if (lane == 0 && cnt > 0.f) {
      atomicAdd(&gcnt[b0], cnt);
      for (int j = 0; j < CC; j++) atomicAdd(&gsum[b0 * CC + j], val[j]);
    }
  } else if (active) {
    atomicAdd(&gcnt[b], cnt);
    for (int j = 0; j < CC; j++) atomicAdd(&gsum[b * CC + j], val[j]);
  }
}

__global__ void k_logsm(const float* __restrict__ gsum, const float* __restrict__ gcnt,
                        float* __restrict__ out) {
  int t = threadIdx.x;
  if (t >= BB) return;
  float gr[CC];
  float c = gcnt[t];
  float m = -INFINITY;
  for (int j = 0; j < CC; j++) {
    gr[j] = gsum[t * CC + j] / c;
    m = fmaxf(m, gr[j]);
  }
  float s = 0.f;
  for (int j = 0; j < CC; j++) s += expf(gr[j] - m);
  float l = logf(s);
  for (int j = 0; j < CC; j++) out[t * CC + j] = gr[j] - m - l;
}

// ---------- host ----------
extern "C" void kernel_launch(void* const* d_in, const int* in_sizes, int n_in,
                              void* d_out, int out_size, void* d_ws, size_t ws_size,
                              hipStream_t stream) {
  const float* x = (const float*)d_in[0];
  const int* src = (const int*)d_in[1];
  const int* dst = (const int*)d_in[2];
  const float* W1 = (const float*)d_in[4];
  const float* b1 = (const float*)d_in[5];
  const float* W2 = (const float*)d_in[6];
  const float* b2 = (const float*)d_in[7];
  const float* Wp1 = (const float*)d_in[8];
  const float* bp1 = (const float*)d_in[9];
  const float* Wp2 = (const float*)d_in[10];
  const float* bp2 = (const float*)d_in[11];
  float* out = (float*)d_out;
  (void)bp1; (void)bp2;  // dst-softmax constant terms cancel in the score

  char* wsb = (char*)d_ws;
  size_t off = 0;
  auto A = [&](size_t bytes) -> char* {
    char* r = wsb + off;
    off = (off + bytes + 255) & ~(size_t)255;
    return r;
  };
  float* h1pre = (float*)A((size_t)NN * HH * 4);
  float* h1out = (float*)A((size_t)NN * HH * 4);
  float* deg = (float*)A((size_t)NN * 4);
  float* dinv = (float*)A((size_t)NN * 4);
  unsigned char* hasloop = (unsigned char*)A(NN);
  unsigned char* addloop = (unsigned char*)A(NN);
  float* aout = (float*)A((size_t)NN * 4);
  float* score = (float*)A((size_t)EE * 4);
  unsigned char* chosen = (unsigned char*)A(EE);
  unsigned char* nv1 = (unsigned char*)A(NN);
  unsigned char* nv2 = (unsigned char*)A(NN);
  float* scale = (float*)A((size_t)NN * 4);
  int* partner = (int*)A((size_t)NN * 4);
  int* merged = (int*)A((size_t)NN * 4);
  int* ns = (int*)A((size_t)EE * 4);
  int* nd = (int*)A((size_t)EE * 4);
  unsigned char* ev1 = (unsigned char*)A(EE);
  unsigned long long* htab = (unsigned long long*)A((size_t)HT_SIZE * 8);
  float* h2pre = (float*)A((size_t)NN * CC * 4);
  float* h2out = (float*)A((size_t)NN * CC * 4);
  unsigned long long* bestA = (unsigned long long*)A((size_t)NN * 8);
  unsigned long long* bestB = (unsigned long long*)A((size_t)NN * 8);
  unsigned char* remG = (unsigned char*)A(NN);
  ulonglong2* recs0 = (ulonglong2*)A((size_t)BB * CAP * 16);
  ulonglong2* recs1 = (ulonglong2*)A((size_t)BB * CAP * 16);
  int* gcntsA = (int*)A((size_t)BB * GPAD * 4);
  int* gcntsB = (int*)A((size_t)BB * GPAD * 4);
  float* gsum = (float*)A((size_t)BB * CC * 4);
  float* gcnt = (float*)A((size_t)BB * 4);
  int* rowstart = (int*)A((size_t)(NN + 1) * 4);
  int* fill = (int*)A((size_t)NN * 4);
  int* bsum = (int*)A((size_t)64 * 4);
  int* csrS = (int*)A((size_t)EE * 4);
  int* csrE = (int*)A((size_t)EE * 4);
  (void)ws_size; (void)n_in; (void)in_sizes; (void)out_size;

  const int GE = ngrid(EE), GN = ngrid(NN);
  const dim3 RG(32, BB);  // global-round grid: 32 blocks x 8 graphs

  // ===== stage 1: GCNConv(384->6) + ReLU =====
  hipMemsetAsync(htab, 0xFF, (size_t)HT_SIZE * 8, stream);
  hipLaunchKernelGGL(k_mm1, dim3((NN + 3) / 4), dim3(TPB), 0, stream, x, W1, h1pre);
  hipLaunchKernelGGL(k_prep, dim3(GN), dim3(TPB), 0, stream, deg, hasloop, gcntsA, gcntsB,
                     gsum, gcnt, (const unsigned char*)nullptr, nv1, scale, merged, partner, bestA, bestB, remG);
  hipLaunchKernelGGL(k_deg, dim3(GE), dim3(TPB), 0, stream, src, dst, (const unsigned char*)nullptr, deg, hasloop);
  hipLaunchKernelGGL(k_scan1, dim3(NBLK), dim3(SCAN_B), 0, stream, deg, rowstart, bsum);
  hipLaunchKernelGGL(k_scan3, dim3(GN), dim3(TPB), 0, stream, rowstart, bsum, fill, deg, hasloop,
                     (const unsigned char*)nullptr, dinv, addloop);
  hipLaunchKernelGGL(k_scatter, dim3(GE), dim3(TPB), 0, stream, src, dst, (const unsigned char*)nullptr, fill, csrS, csrE);
  hipLaunchKernelGGL(k_agg_fin<HH>, dim3(GN), dim3(TPB), 0, stream, rowstart, csrS, dinv, addloop, h1pre, b1, Wp1, aout, h1out, 1);

  // ===== edge pool 1 =====
  hipLaunchKernelGGL(k_smscore, dim3(GN), dim3(TPB), 0, stream, rowstart, csrS, csrE, aout, remG, score, bestA);
  hipLaunchKernelGGL(k_r1sel, dim3(GE), dim3(TPB), 0, stream, src, dst, score, (const unsigned char*)nullptr, remG, bestA, bestB, chosen, recs0, gcntsA);
  // global rounds 2-6 (split post/sel — R7 lesson: fusing stalls commits)
  hipLaunchKernelGGL(k_gpost, RG, dim3(TPB), 0, stream, recs0, gcntsA, remG, bestB, gcntsB);
  hipLaunchKernelGGL(k_gsel, RG, dim3(TPB), 0, stream, recs0, gcntsA, remG, bestB, bestA, chosen, recs1, gcntsB);
  hipLaunchKernelGGL(k_gpost, RG, dim3(TPB), 0, stream, recs1, gcntsB, remG, bestA, gcntsA);
  hipLaunchKernelGGL(k_gsel, RG, dim3(TPB), 0, stream, recs1, gcntsB, remG, bestA, bestB, chosen, recs0, gcntsA);
  hipLaunchKernelGGL(k_gpost, RG, dim3(TPB), 0, stream, recs0, gcntsA, remG, bestB, gcntsB);
  hipLaunchKernelGGL(k_gsel, RG, dim3(TPB), 0, stream, recs0, gcntsA, remG, bestB, bestA, chosen, recs1, gcntsB);
  hipLaunchKernelGGL(k_gpost, RG, dim3(TPB), 0, stream, recs1, gcntsB, remG, bestA, gcntsA);
  hipLaunchKernelGGL(k_gsel, RG, dim3(TPB), 0, stream, recs1, gcntsB, remG, bestA, bestB, chosen, recs0, gcntsA);
  hipLaunchKernelGGL(k_gpost, RG, dim3(TPB), 0, stream, recs0, gcntsA, remG, bestB, gcntsB);
  hipLaunchKernelGGL(k_gsel, RG, dim3(TPB), 0, stream, recs0, gcntsA, remG, bestB, bestA, chosen, recs1, gcntsB);
  // LDS tail
  hipLaunchKernelGGL(k_match_g, dim3(BB), dim3(1024), 0, stream, recs1, recs0, gcntsB, remG, chosen);
  hipLaunchKernelGGL(k_pool_edge, dim3(GE), dim3(TPB), 0, stream, src, dst, chosen, score, nv1, scale, partner, merged);
  hipLaunchKernelGGL(k_newx_prep, dim3(GN), dim3(TPB), 0, stream, h1out, W2, h2pre,
                     deg, hasloop, gcntsA, gcntsB, gsum, gcnt, nv1, nv2, scale, partner, bestA, bestB, remG);
  hipLaunchKernelGGL(k_remap_ins, dim3(GE), dim3(TPB), 0, stream, src, dst, merged, ns, nd, htab);

  // ===== stage 2: GCNConv(6->10) =====
  hipLaunchKernelGGL(k_dedup_deg, dim3(GE), dim3(TPB), 0, stream, ns, nd, htab, ev1, deg, hasloop);
  hipLaunchKernelGGL(k_scan1, dim3(NBLK), dim3(SCAN_B), 0, stream, deg, rowstart, bsum);
  hipLaunchKernelGGL(k_scan3, dim3(GN), dim3(TPB), 0, stream, rowstart, bsum, fill, deg, hasloop,
                     (const unsigned char*)nv1, dinv, addloop);
  hipLaunchKernelGGL(k_scatter, dim3(GE), dim3(TPB), 0, stream, ns, nd, (const unsigned char*)ev1, fill, csrS, csrE);
  hipLaunchKernelGGL(k_agg_fin<CC>, dim3(GN), dim3(TPB), 0, stream, rowstart, csrS, dinv, addloop, h2pre, b2, Wp2, aout, h2out, 0);

  // ===== edge pool 2 =====
  hipLaunchKernelGGL(k_smscore, dim3(GN), dim3(TPB), 0, stream, rowstart, csrS, csrE, aout, remG, score, bestA);
  hipLaunchKernelGGL(k_r1sel, dim3(GE), dim3(TPB), 0, stream, ns, nd, score, (const unsigned char*)ev1, remG, bestA, bestB, chosen, recs0, gcntsA);
  hipLaunchKernelGGL(k_gpost, RG, dim3(TPB), 0, stream, recs0, gcntsA, remG, bestB, gcntsB);
  hipLaunchKernelGGL(k_gsel, RG, dim3(TPB), 0, stream, recs0, gcntsA, remG, bestB, bestA, chosen, recs1, gcntsB);
  hipLaunchKernelGGL(k_gpost, RG, dim3(TPB), 0, stream, recs1, gcntsB, remG, bestA, gcntsA);
  hipLaunchKernelGGL(k_gsel, RG, dim3(TPB), 0, stream, recs1, gcntsB, remG, bestA, bestB, chosen, recs0, gcntsA);
  hipLaunchKernelGGL(k_gpost, RG, dim3(TPB), 0, stream, recs0, gcntsA, remG, bestB, gcntsB);
  hipLaunchKernelGGL(k_gsel, RG, dim3(TPB), 0, stream, recs0, gcntsA, remG, bestB, bestA, chosen, recs1, gcntsB);
  hipLaunchKernelGGL(k_gpost, RG, dim3(TPB), 0, stream, recs1, gcntsB, remG, bestA, gcntsA);
  hipLaunchKernelGGL(k_gsel, RG, dim3(TPB), 0, stream, recs1, gcntsB, remG, bestA, bestB, chosen, recs0, gcntsA);
  hipLaunchKernelGGL(k_gpost, RG, dim3(TPB), 0, stream, recs0, gcntsA, remG, bestB, gcntsB);
  hipLaunchKernelGGL(k_gsel, RG, dim3(TPB), 0, stream, recs0, gcntsA, remG, bestB, bestA, chosen, recs1, gcntsB);
  hipLaunchKernelGGL(k_match_g, dim3(BB), dim3(1024), 0, stream, recs1, recs0, gcntsB, remG, chosen);
  hipLaunchKernelGGL(k_pool_edge, dim3(GE), dim3(TPB), 0, stream, ns, nd, chosen, score, nv2, scale, partner, (int*)nullptr);

  // ===== readout =====
  hipLaunchKernelGGL(k_newx_pool, dim3(GN), dim3(TPB), 0, stream, h2out, partner, scale, nv2, gsum, gcnt);
  hipLaunchKernelGGL(k_logsm, dim3(1), dim3(64), 0, stream, gsum, gcnt, out);
}

// Round 13
// 1324.107 us; speedup vs baseline: 99.6402x; 1.0044x over previous
//
#include <hip/hip_runtime.h>
#include <math.h>

#define NN 60000
#define BB 8
#define GS 7500   // nodes per graph
#define FF 384
#define EE 600000
#define HH 6
#define CC 10
#define HT_BITS 20
#define HT_SIZE (1u << HT_BITS)
#define HT_MASK (HT_SIZE - 1u)
#define TPB 256
#define CAP 80000  // per-graph edge capacity
#define REMW ((GS + 31) / 32)
#define GPAD 32    // counter padding: one per 128B (R3 lesson)
#define SCAN_B 1024
#define NBLK ((NN + SCAN_B - 1) / SCAN_B)  // 59
static_assert(NBLK <= 64, "scan3 wave-scan assumes <=64 blocks");
static_assert((HH % 2) == 0 && (CC % 2) == 0, "float2 paths assume even fd");

static inline int ngrid(int n) { return (n + TPB - 1) / TPB; }

// ---------- helpers ----------
__device__ __forceinline__ unsigned long long mkprio(float sc, int e) {
  return (((unsigned long long)__float_as_uint(sc)) << 32) |
         (unsigned int)(~(unsigned int)e);
}
// commit-site application of EdgePooling bookkeeping (replaces k_pool_edge).
// Committed edges form a matching -> per-node writes are disjoint, race-free.
__device__ __forceinline__ void apply_commit(int s, int d, float sc,
                                             unsigned char* nvout, float* scale,
                                             int* partner, int* merged) {
  scale[s] = sc;
  if (merged) merged[d] = s;
  if (s != d) {
    nvout[d] = 0;
    partner[s] = d;
  }
}

// ---------- stage 1 matmul: h1pre = x @ W1 ----------
__global__ void k_mm1(const float* __restrict__ x, const float* __restrict__ W,
                      float* __restrict__ out) {
  __shared__ float Ws[FF * HH];
  for (int i = threadIdx.x; i < FF * HH; i += blockDim.x) Ws[i] = W[i];
  __syncthreads();
  int wave = threadIdx.x >> 6, lane = threadIdx.x & 63;
  int node = blockIdx.x * 4 + wave;
  if (node >= NN) return;
  const float* xr = x + (size_t)node * FF;
  float acc[HH] = {0.f, 0.f, 0.f, 0.f, 0.f, 0.f};
  for (int k = lane; k < FF; k += 64) {
    float xv = xr[k];
#pragma unroll
    for (int j = 0; j < HH; j++) acc[j] += xv * Ws[k * HH + j];
  }
#pragma unroll
  for (int j = 0; j < HH; j++) {
#pragma unroll
    for (int o = 32; o > 0; o >>= 1) acc[j] += __shfl_down(acc[j], o, 64);
  }
  if (lane == 0) {
#pragma unroll
    for (int j = 0; j < HH; j++) out[(size_t)node * HH + j] = acc[j];
  }
}

// ---------- fused per-stage init (stage 1 only; stage 2 fused into k_newx_prep) ----------
__global__ void k_prep(float* __restrict__ deg, unsigned char* __restrict__ hasloop,
                       int* __restrict__ gcntsA,
                       int* __restrict__ gcntsB, float* __restrict__ gsum,
                       float* __restrict__ gcnt, const unsigned char* __restrict__ nvin,
                       unsigned char* __restrict__ nvout, float* __restrict__ scale,
                       int* __restrict__ merged, int* __restrict__ partner,
                       unsigned long long* __restrict__ bestA,
                       unsigned long long* __restrict__ bestB,
                       unsigned char* __restrict__ remG) {
  int v = blockIdx.x * blockDim.x + threadIdx.x;
  if (v >= NN) return;
  deg[v] = 0.f;
  hasloop[v] = 0;
  unsigned char nvv = nvin ? nvin[v] : 1;
  nvout[v] = nvv;
  remG[v] = nvv;
  bestA[v] = 0ULL;
  bestB[v] = 0ULL;
  scale[v] = 1.0f;
  if (merged) merged[v] = -1;
  partner[v] = -1;
  if (v < BB * GPAD) { gcntsA[v] = 0; gcntsB[v] = 0; }
  if (v < BB * CC) gsum[v] = 0.f;
  if (v < BB) gcnt[v] = 0.f;
}

// ---------- generic GCN conv pieces ----------
__global__ void k_deg(const int* __restrict__ src, const int* __restrict__ dst,
                      const unsigned char* __restrict__ ev, float* __restrict__ deg,
                      unsigned char* __restrict__ hasloop) {
  int e = blockIdx.x * blockDim.x + threadIdx.x;
  if (e >= EE) return;
  if (ev && !ev[e]) return;
  int d = dst[e];
  atomicAdd(&deg[d], 1.0f);
  if (src[e] == d) hasloop[d] = 1;
}

// ---------- CSR build: scan of deg -> rowstart, then scatter ----------
__global__ __launch_bounds__(1024) void k_scan1(const float* __restrict__ deg,
                                                int* __restrict__ rowstart,
                                                int* __restrict__ bsum) {
  __shared__ int tmp[SCAN_B];
  int t = threadIdx.x;
  int i = blockIdx.x * SCAN_B + t;
  int v = (i < NN) ? (int)deg[i] : 0;
  tmp[t] = v;
  __syncthreads();
  for (int o = 1; o < SCAN_B; o <<= 1) {
    int y = (t >= o) ? tmp[t - o] : 0;
    __syncthreads();
    tmp[t] += y;
    __syncthreads();
  }
  if (i < NN) rowstart[i] = tmp[t] - v;  // exclusive within block
  if (t == SCAN_B - 1) bsum[blockIdx.x] = tmp[t];
}

// scan fixup (each block wave-scans the 59 block sums itself) + fused dinv/addloop
__global__ void k_scan3(int* __restrict__ rowstart, const int* __restrict__ bsum,
                        int* __restrict__ fill, const float* __restrict__ deg,
                        const unsigned char* __restrict__ hasloop,
                        const unsigned char* __restrict__ nv, float* __restrict__ dinv,
                        unsigned char* __restrict__ addloop) {
  __shared__ int offs[64];
  __shared__ int total;
  int t = threadIdx.x;
  if (t < 64) {
    int v = (t < NBLK) ? bsum[t] : 0;
    int x = v;
#pragma unroll
    for (int o = 1; o < 64; o <<= 1) {
      int y = __shfl_up(x, o, 64);
      if (t >= o) x += y;
    }
    offs[t] = x - v;          // exclusive block offset
    if (t == 63) total = x;   // grand total
  }
  __syncthreads();
  int i = blockIdx.x * blockDim.x + t;
  if (i >= NN) return;
  int r = rowstart[i] + offs[i >> 10];  // SCAN_B == 1024
  rowstart[i] = r;
  fill[i] = r;
  if (i == NN - 1) rowstart[NN] = total;
  int nvv = nv ? (int)nv[i] : 1;
  unsigned char al = (nvv && !hasloop[i]) ? 1 : 0;
  float d = deg[i] + (float)al;
  dinv[i] = d > 0.f ? 1.0f / sqrtf(fmaxf(d, 1e-12f)) : 0.f;
  addloop[i] = al;
}

__global__ void k_scatter(const int* __restrict__ src, const int* __restrict__ dst,
                          const unsigned char* __restrict__ ev, int* __restrict__ fill,
                          int* __restrict__ csrS, int* __restrict__ csrE) {
  int e = blockIdx.x * blockDim.x + threadIdx.x;
  if (e >= EE) return;
  if (ev && !ev[e]) return;
  int d = dst[e];
  int p = atomicAdd(&fill[d], 1);
  csrS[p] = src[e];
  csrE[p] = e;
}

// fused gather aggregation + finalize + per-node src-score a[v] = out_row . Wp[0:FD]
// (EdgePool raw score is separable: raw[e] = a[src] + (h[dst].Wp[fd:]+bp); the dst
// term is constant within each dst softmax group and cancels -> only a[] needed.)
template <int FD>
__global__ void k_agg_fin(const int* __restrict__ rowstart, const int* __restrict__ csrS,
                          const float* __restrict__ dinv, const unsigned char* __restrict__ addloop,
                          const float* __restrict__ h, const float* __restrict__ b,
                          const float* __restrict__ Wp, float* __restrict__ aout,
                          float* __restrict__ out, int relu) {
  int v = blockIdx.x * blockDim.x + threadIdx.x;
  if (v >= NN) return;
  int b0 = rowstart[v], b1 = rowstart[v + 1];
  float acc[FD];
#pragma unroll
  for (int j = 0; j < FD; j++) acc[j] = 0.f;
  float dv = dinv[v];
  for (int i = b0; i < b1; i++) {
    int s = csrS[i];
    float c = dinv[s] * dv;  // per-edge coef, matches reference factoring
    const float2* hr2 = (const float2*)(h + (size_t)s * FD);
#pragma unroll
    for (int j = 0; j < FD / 2; j++) {
      float2 hv = hr2[j];
      acc[2 * j] += hv.x * c;
      acc[2 * j + 1] += hv.y * c;
    }
  }
  float cl = addloop[v] ? dv * dv : 0.f;
  const float* hv = h + (size_t)v * FD;
  float av = 0.f;
#pragma unroll
  for (int j = 0; j < FD; j++) {
    float o = acc[j] + cl * hv[j] + b[j];
    if (relu) o = fmaxf(o, 0.f);
    out[(size_t)v * FD + j] = o;
    av += o * Wp[j];
  }
  aout[v] = av;
}

// fused softmax stats + score + bestA posting, a[]-factorized (dst term cancels).
__global__ void k_smscore(const int* __restrict__ rowstart, const int* __restrict__ csrS,
                          const int* __restrict__ csrE, const float* __restrict__ a,
                          const unsigned char* __restrict__ remG, float* __restrict__ score,
                          unsigned long long* __restrict__ bestA) {
  int v = blockIdx.x * blockDim.x + threadIdx.x;
  if (v >= NN) return;
  int b0 = rowstart[v], b1 = rowstart[v + 1];
  if (b0 == b1) return;
  float ma = -INFINITY;
  for (int i = b0; i < b1; i++) ma = fmaxf(ma, a[csrS[i]]);
  float s = 0.f;
  for (int i = b0; i < b1; i++) s += expf(a[csrS[i]] - ma);
  if (!remG[v]) return;
  float sd = s > 0.f ? s : 1.0f;
  unsigned long long lb = 0ULL;
  for (int i = b0; i < b1; i++) {
    int sv = csrS[i];
    if (!remG[sv]) continue;
    int e = csrE[i];
    float sc = expf(a[sv] - ma) / sd + 0.5f;
    score[e] = sc;
    unsigned long long p = mkprio(sc, e);
    if (p > lb) lb = p;
    if (sv != v && p > bestA[sv]) atomicMax(&bestA[sv], p);
  }
  if (lb > bestA[v]) atomicMax(&bestA[v], lb);
}

// ---------- round 1 select + compact; survivors zero bestB; commits write pool state ----------
__global__ void k_r1sel(const int* __restrict__ src, const int* __restrict__ dst,
                        const float* __restrict__ score, const unsigned char* __restrict__ ev,
                        unsigned char* __restrict__ remG,
                        const unsigned long long* __restrict__ bestA,
                        unsigned long long* __restrict__ bestB,
                        unsigned char* __restrict__ nvout, float* __restrict__ scale,
                        int* __restrict__ partner, int* __restrict__ merged,
                        ulonglong2* __restrict__ recs, int* __restrict__ gcnts) {
  __shared__ int wcnt[TPB / 64][BB];
  __shared__ int bbase[BB];
  int e = blockIdx.x * blockDim.x + threadIdx.x;
  int w = threadIdx.x >> 6, lane = threadIdx.x & 63;
  int keep = 0, s = 0, d = 0, g = 0;
  unsigned long long p = 0;
  if (e < EE && (!ev || ev[e])) {
    s = src[e];
    d = dst[e];
    g = s / GS;
    if (remG[s] && remG[d]) {
      float sc = score[e];
      p = mkprio(sc, e);
      if (bestA[s] == p && bestA[d] == p) {
        remG[s] = 0;
        remG[d] = 0;
        apply_commit(s, d, sc, nvout, scale, partner, merged);
      } else {
        keep = 1;
        bestB[s] = 0ULL;  // benign write race; next round's buffer
        bestB[d] = 0ULL;
      }
    }
  }
  int myrank = 0;
#pragma unroll
  for (int gg = 0; gg < BB; gg++) {
    unsigned long long m = __ballot(keep && g == gg);
    if (keep && g == gg) myrank = __popcll(m & ((1ULL << lane) - 1ULL));
    if (lane == 0) wcnt[w][gg] = __popcll(m);
  }
  __syncthreads();
  if (threadIdx.x < BB) {
    int gg = threadIdx.x, tot = 0;
#pragma unroll
    for (int ww = 0; ww < TPB / 64; ww++) {
      int c = wcnt[ww][gg];
      wcnt[ww][gg] = tot;
      tot += c;
    }
    bbase[gg] = tot ? atomicAdd(&gcnts[gg * GPAD], tot) : 0;
  }
  __syncthreads();
  if (keep)
    recs[(size_t)g * CAP + bbase[g] + wcnt[w][g] + myrank] =
        make_ulonglong2(p, (((unsigned long long)(unsigned int)s) << 32) | (unsigned int)d);
}

// ---------- generic global round (full GPU) over compacted lists ----------
// R7 lesson: do NOT fuse post into the select kernel. R9 lesson: do NOT use
// cooperative grid.sync (forces L2 flush on gfx950 -> 100MB refetch/round).
__global__ void k_gpost(const ulonglong2* __restrict__ recs, const int* __restrict__ gcnts,
                        const unsigned char* __restrict__ remG,
                        unsigned long long* __restrict__ bestC, int* __restrict__ gcntsOut) {
  int g = blockIdx.y;
  if (blockIdx.x == 0 && threadIdx.x == 0) gcntsOut[g * GPAD] = 0;
  int n = gcnts[g * GPAD];
  const ulonglong2* lst = recs + (size_t)g * CAP;
  int stride = gridDim.x * blockDim.x;
  for (int i = blockIdx.x * blockDim.x + threadIdx.x; i < n; i += stride) {
    ulonglong2 r = lst[i];
    int s = (int)(r.y >> 32), d = (int)(r.y & 0xFFFFFFFFu);
    if (remG[s] && remG[d]) {
      if (r.x > bestC[s]) atomicMax(&bestC[s], r.x);
      if (d != s && r.x > bestC[d]) atomicMax(&bestC[d], r.x);
    }
  }
}

// sel: winners commit (direct pool-state writes); survivors -> out list + zero bestN
__global__ void k_gsel(const ulonglong2* __restrict__ recsIn, const int* __restrict__ gcntsIn,
                       unsigned char* __restrict__ remG,
                       const unsigned long long* __restrict__ bestC,
                       unsigned long long* __restrict__ bestN,
                       unsigned char* __restrict__ nvout, float* __restrict__ scale,
                       int* __restrict__ partner, int* __restrict__ merged,
                       ulonglong2* __restrict__ recsOut, int* __restrict__ gcntsOut) {
  int g = blockIdx.y;
  int n = gcntsIn[g * GPAD];
  const ulonglong2* lst = recsIn + (size_t)g * CAP;
  ulonglong2* outl = recsOut + (size_t)g * CAP;
  int lane = threadIdx.x & 63;
  int stride = gridDim.x * blockDim.x;
  for (int i = blockIdx.x * blockDim.x + threadIdx.x; i - lane < n; i += stride) {
    int keep = 0;
    ulonglong2 r;
    if (i < n) {
      r = lst[i];
      int s = (int)(r.y >> 32), d = (int)(r.y & 0xFFFFFFFFu);
      if (remG[s] && remG[d]) {
        if (bestC[s] == r.x && bestC[d] == r.x) {
          remG[s] = 0;
          remG[d] = 0;
          float sc = __uint_as_float((unsigned int)(r.x >> 32));  // bit-exact score
          apply_commit(s, d, sc, nvout, scale, partner, merged);
        } else {
          keep = 1;
          bestN[s] = 0ULL;
          bestN[d] = 0ULL;
        }
      }
    }
    unsigned long long m = __ballot(keep);
    int tot = __popcll(m);
    int pre = __popcll(m & ((1ULL << lane) - 1ULL));
    int b0 = 0;
    if (lane == 0 && tot) b0 = atomicAdd(&gcntsOut[g * GPAD], tot);
    b0 = __shfl(b0, 0, 64);
    if (keep) outl[b0 + pre] = r;
  }
}

// ---------- matching tail: per-graph LDS fixpoint (R8-verified form; commits write pool state) ----------
// R2/R3 + R10 lesson: do NOT register-cache records across the P1/P2/P3 barriers
// (2/2 attempts degenerated to O(1)-commit rounds, ~1000x slower). Always re-read
// the list per phase. P3's clear doubles as the cnt_next handoff barrier.
__global__ __launch_bounds__(1024) void k_match_g(ulonglong2* __restrict__ recs0,
                                                  ulonglong2* __restrict__ recs1,
                                                  const int* __restrict__ gcnts,
                                                  const unsigned char* __restrict__ remG,
                                                  unsigned char* __restrict__ nvout,
                                                  float* __restrict__ scale,
                                                  int* __restrict__ partner,
                                                  int* __restrict__ merged) {
  __shared__ unsigned long long best[GS];
  __shared__ unsigned int remB[REMW];
  __shared__ int cnt_next;
  const int g = blockIdx.x;
  const int base = g * GS;
  const int t = threadIdx.x, nth = blockDim.x;
  const int lane = t & 63;

  for (int w = t; w < REMW; w += nth) {
    unsigned int bits = 0;
    int v0 = w * 32;
    if (v0 + 32 <= GS) {
      const unsigned int* p4 = (const unsigned int*)(remG + base + v0);
#pragma unroll
      for (int q = 0; q < 8; q++) {
        unsigned int x4 = p4[q];
        bits |= ((x4 & 1u) << (q * 4)) | (((x4 >> 8) & 1u) << (q * 4 + 1)) |
                (((x4 >> 16) & 1u) << (q * 4 + 2)) | (((x4 >> 24) & 1u) << (q * 4 + 3));
      }
    } else {
      for (int b = 0; b < 32; b++) {
        int v = v0 + b;
        if (v < GS) bits |= (remG[base + v] ? 1u : 0u) << b;
      }
    }
    remB[w] = bits;
  }
  for (int i = t; i < GS; i += nth) best[i] = 0ULL;
  __syncthreads();

  ulonglong2* bufs[2] = {recs0 + (size_t)g * CAP, recs1 + (size_t)g * CAP};
  int n = gcnts[g * GPAD];
  int cur = 0;
  int guard = 0;

  while (n > 0) {
    if (++guard > 100000) break;  // dormant watchdog (practical rounds ~30)
    // P1: live edges post priority (x4 batched loads for MLP)
    for (int i0 = 0; i0 < n; i0 += nth * 4) {
      ulonglong2 r[4];
      int have[4];
#pragma unroll
      for (int k = 0; k < 4; k++) {
        int i = i0 + t + k * nth;
        have[k] = i < n;
        if (have[k]) r[k] = bufs[cur][i];
      }
#pragma unroll
      for (int k = 0; k < 4; k++) {
        if (!have[k]) continue;
        int ls = (int)(r[k].y >> 32) - base, ld = (int)(r[k].y & 0xFFFFFFFFu) - base;
        if (((remB[ls >> 5] >> (ls & 31)) & 1u) && ((remB[ld >> 5] >> (ld & 31)) & 1u)) {
          atomicMax(&best[ls], r[k].x);
          if (ld != ls) atomicMax(&best[ld], r[k].x);
        }
      }
    }
    if (t == 0) cnt_next = 0;
    __syncthreads();
    // P2: winners commit; survivors compact
    for (int i0 = 0; i0 < n; i0 += nth * 4) {
      ulonglong2 r[4];
      int have[4];
#pragma unroll
      for (int k = 0; k < 4; k++) {
        int i = i0 + t + k * nth;
        have[k] = i < n;
        if (have[k]) r[k] = bufs[cur][i];
      }
#pragma unroll
      for (int k = 0; k < 4; k++) {
        int keep = 0;
        int ls = 0, ld = 0;
        if (have[k]) {
          ls = (int)(r[k].y >> 32) - base;
          ld = (int)(r[k].y & 0xFFFFFFFFu) - base;
          if (((remB[ls >> 5] >> (ls & 31)) & 1u) && ((remB[ld >> 5] >> (ld & 31)) & 1u)) {
            if (best[ls] == r[k].x && best[ld] == r[k].x) {
              atomicAnd(&remB[ls >> 5], ~(1u << (ls & 31)));
              atomicAnd(&remB[ld >> 5], ~(1u << (ld & 31)));
              float sc = __uint_as_float((unsigned int)(r[k].x >> 32));
              apply_commit(base + ls, base + ld, sc, nvout, scale, partner, merged);
            } else {
              keep = 1;
            }
          }
        }
        unsigned long long m = __ballot(keep);
        int tot = __popcll(m);
        int pre = __popcll(m & ((1ULL << lane) - 1ULL));
        int b0 = 0;
        if (lane == 0 && tot) b0 = atomicAdd(&cnt_next, tot);
        b0 = __shfl(b0, 0, 64);
        if (keep) bufs[cur ^ 1][b0 + pre] = r[k];
      }
    }
    __syncthreads();
    n = cnt_next;
    // P3: hybrid clear — survivor-driven for small rounds, full wipe otherwise
    if (n < 4096) {
      for (int i = t; i < n; i += nth) {
        ulonglong2 r = bufs[cur ^ 1][i];
        best[(int)(r.y >> 32) - base] = 0ULL;
        best[(int)(r.y & 0xFFFFFFFFu) - base] = 0ULL;
      }
    } else {
      for (int i = t; i < GS; i += nth) best[i] = 0ULL;
    }
    __syncthreads();
    cur ^= 1;
  }
}

// fused: newx1 -> h2pre = newx1 @ W2, PLUS stage-2 per-node init (was k_prep).
// Per-thread order: read stage-1 partner/scale/nv1 and compute mm2 FIRST, then
// reset the per-node matching state for stage 2 (program order, no cross-thread
// hazards; merged[] is untouched, k_remap_ins still reads it afterwards).
__global__ void k_newx_prep(const float* __restrict__ h1, const float* __restrict__ W2,
                            float* __restrict__ h2pre,
                            float* __restrict__ deg, unsigned char* __restrict__ hasloop,
                            int* __restrict__ gcntsA, int* __restrict__ gcntsB,
                            float* __restrict__ gsum, float* __restrict__ gcnt,
                            const unsigned char* __restrict__ nv1,
                            unsigned char* __restrict__ nv2, float* __restrict__ scale,
                            int* __restrict__ partner,
                            unsigned long long* __restrict__ bestA,
                            unsigned long long* __restrict__ bestB,
                            unsigned char* __restrict__ remG) {
  int v = blockIdx.x * blockDim.x + threadIdx.x;
  if (v >= NN) return;
  // --- newx_mm2 (stage-1 state reads) ---
  float sc = scale[v];
  unsigned char nvv = nv1[v];
  int ok = nvv;
  int p = partner[v];
  float nx[HH];
#pragma unroll
  for (int j = 0; j < HH; j++) {
    float a = h1[(size_t)v * HH + j];
    if (p >= 0) a += h1[(size_t)p * HH + j];
    nx[j] = ok ? a * sc : 0.f;
  }
#pragma unroll
  for (int c = 0; c < CC; c++) {
    float a = 0.f;
#pragma unroll
    for (int j = 0; j < HH; j++) a += nx[j] * W2[j * CC + c];
    h2pre[(size_t)v * CC + c] = a;
  }
  // --- stage-2 prep (writes after reads) ---
  deg[v] = 0.f;
  hasloop[v] = 0;
  nv2[v] = nvv;
  remG[v] = nvv;
  bestA[v] = 0ULL;
  bestB[v] = 0ULL;
  scale[v] = 1.0f;
  partner[v] = -1;
  if (v < BB * GPAD) { gcntsA[v] = 0; gcntsB[v] = 0; }
  if (v < BB * CC) gsum[v] = 0.f;
  if (v < BB) gcnt[v] = 0.f;
}

// fused remap + dedup insert
__device__ __forceinline__ unsigned int ht_hash(unsigned long long key) {
  return (unsigned int)((key * 0x9E3779B97F4A7C15ULL) >> 44) & HT_MASK;
}

__global__ void k_remap_ins(const int* __restrict__ src, const int* __restrict__ dst,
                            const int* __restrict__ merged, int* __restrict__ ns,
                            int* __restrict__ nd, unsigned long long* __restrict__ htab) {
  int e = blockIdx.x * blockDim.x + threadIdx.x;
  if (e >= EE) return;
  int s = src[e], d = dst[e];
  int ms = merged[s], md = merged[d];
  int a = ms >= 0 ? ms : s;
  int b = md >= 0 ? md : d;
  ns[e] = a;
  nd[e] = b;
  unsigned long long key =
      (unsigned long long)((((unsigned int)a) << 16) | (unsigned int)b);
  unsigned long long val = (key << 32) | (unsigned int)e;
  unsigned int h = ht_hash(key);
  for (;;) {
    unsigned long long curv = htab[h];
    if (curv == ~0ULL) {
      unsigned long long prev = atomicCAS(&htab[h], ~0ULL, val);
      if (prev == ~0ULL) break;
      curv = prev;
    }
    if ((curv >> 32) == key) {
      if ((curv & 0xFFFFFFFFULL) > (unsigned long long)(unsigned int)e)
        atomicMin(&htab[h], val);
      break;
    }
    h = (h + 1) & HT_MASK;
  }
}

// fused dedup-mark + stage2 degree count (same edge domain; deg pre-zeroed by k_newx_prep)
__global__ void k_dedup_deg(const int* __restrict__ ns, const int* __restrict__ nd,
                            const unsigned long long* __restrict__ htab,
                            unsigned char* __restrict__ evout, float* __restrict__ deg,
                            unsigned char* __restrict__ hasloop) {
  int e = blockIdx.x * blockDim.x + threadIdx.x;
  if (e >= EE) return;
  unsigned long long key =
      (unsigned long long)((((unsigned int)ns[e]) << 16) | (unsigned int)nd[e]);
  unsigned int h = ht_hash(key);
  for (;;) {
    unsigned long long curv = htab[h];
    if ((curv >> 32) == key) {
      unsigned char ev = ((curv & 0xFFFFFFFFULL) == (unsigned long long)(unsigned int)e) ? 1 : 0;
      evout[e] = ev;
      if (ev) {
        int d = nd[e];
        atomicAdd(&deg[d], 1.0f);
        if (ns[e] == d) hasloop[d] = 1;
      }
      return;
    }
    h = (h + 1) & HT_MASK;
  }
}

// fused: newx2 (never materialized) -> graph mean-pool accumulate
__global__ void k_newx_pool(const float* __restrict__ h2, const int* __restrict__ partner,
                            const float* __restrict__ scale, const unsigned char* __restrict__ nv,
                            float* __restrict__ gsum, float* __restrict__ gcnt) {
  int v = blockIdx.x * blockDim.x + threadIdx.x;
  int lane = threadIdx.x & 63;
  int b = (v < NN ? v : NN - 1) / GS;
  int active = (v < NN) && nv[v];
  float cnt = active ? 1.f : 0.f;
  float val[CC];
  if (active) {
    float sc = scale[v];
    int p = partner[v];
    for (int j = 0; j < CC; j++) {
      float a = h2[(size_t)v * CC + j];
      if (p >= 0) a += h2[(size_t)p * CC + j];
      val[j] = a * sc;
    }
  } else {
    for (int j = 0; j < CC; j++) val[j] = 0.f;
  }
  int b0 = __shfl(b, 0, 64);
  unsigned long long same = __ballot(b == b0);
  if (same == ~0ULL) {
    for (int o = 32; o > 0; o >>= 1) {
      cnt += __shfl_down(cnt, o, 64);
      for (int j = 0; j < CC; j++) val[j] += __shfl_down(val[j], o, 64);
    }
    if (lane == 0 && cnt > 0.f) {
      atomicAdd(&gcnt[b0], cnt);
      for (int j = 0; j < CC; j++) atomicAdd(&gsum[b0 * CC + j], val[j]);
    }
  } else if (active) {
    atomicAdd(&gcnt[b], cnt);
    for (int j = 0; j < CC; j++) atomicAdd(&gsum[b * CC + j], val[j]);
  }
}

__global__ void k_logsm(const float* __restrict__ gsum, const float* __restrict__ gcnt,
                        float* __restrict__ out) {
  int t = threadIdx.x;
  if (t >= BB) return;
  float gr[CC];
  float c = gcnt[t];
  float m = -INFINITY;
  for (int j = 0; j < CC; j++) {
    gr[j] = gsum[t * CC + j] / c;
    m = fmaxf(m, gr[j]);
  }
  float s = 0.f;
  for (int j = 0; j < CC; j++) s += expf(gr[j] - m);
  float l = logf(s);
  for (int j = 0; j < CC; j++) out[t * CC + j] = gr[j] - m - l;
}

// ---------- host ----------
extern "C" void kernel_launch(void* const* d_in, const int* in_sizes, int n_in,
                              void* d_out, int out_size, void* d_ws, size_t ws_size,
                              hipStream_t stream) {
  const float* x = (const float*)d_in[0];
  const int* src = (const int*)d_in[1];
  const int* dst = (const int*)d_in[2];
  const float* W1 = (const float*)d_in[4];
  const float* b1 = (const float*)d_in[5];
  const float* W2 = (const float*)d_in[6];
  const float* b2 = (const float*)d_in[7];
  const float* Wp1 = (const float*)d_in[8];
  const float* bp1 = (const float*)d_in[9];
  const float* Wp2 = (const float*)d_in[10];
  const float* bp2 = (const float*)d_in[11];
  float* out = (float*)d_out;
  (void)bp1; (void)bp2;  // dst-softmax constant terms cancel in the score

  char* wsb = (char*)d_ws;
  size_t off = 0;
  auto A = [&](size_t bytes) -> char* {
    char* r = wsb + off;
    off = (off + bytes + 255) & ~(size_t)255;
    return r;
  };
  float* h1pre = (float*)A((size_t)NN * HH * 4);
  float* h1out = (float*)A((size_t)NN * HH * 4);
  float* deg = (float*)A((size_t)NN * 4);
  float* dinv = (float*)A((size_t)NN * 4);
  unsigned char* hasloop = (unsigned char*)A(NN);
  unsigned char* addloop = (unsigned char*)A(NN);
  float* aout = (float*)A((size_t)NN * 4);
  float* score = (float*)A((size_t)EE * 4);
  unsigned char* nv1 = (unsigned char*)A(NN);
  unsigned char* nv2 = (unsigned char*)A(NN);
  float* scale = (float*)A((size_t)NN * 4);
  int* partner = (int*)A((size_t)NN * 4);
  int* merged = (int*)A((size_t)NN * 4);
  int* ns = (int*)A((size_t)EE * 4);
  int* nd = (int*)A((size_t)EE * 4);
  unsigned char* ev1 = (unsigned char*)A(EE);
  unsigned long long* htab = (unsigned long long*)A((size_t)HT_SIZE * 8);
  float* h2pre = (float*)A((size_t)NN * CC * 4);
  float* h2out = (float*)A((size_t)NN * CC * 4);
  unsigned long long* bestA = (unsigned long long*)A((size_t)NN * 8);
  unsigned long long* bestB = (unsigned long long*)A((size_t)NN * 8);
  unsigned char* remG = (unsigned char*)A(NN);
  ulonglong2* recs0 = (ulonglong2*)A((size_t)BB * CAP * 16);
  ulonglong2* recs1 = (ulonglong2*)A((size_t)BB * CAP * 16);
  int* gcntsA = (int*)A((size_t)BB * GPAD * 4);
  int* gcntsB = (int*)A((size_t)BB * GPAD * 4);
  float* gsum = (float*)A((size_t)BB * CC * 4);
  float* gcnt = (float*)A((size_t)BB * 4);
  int* rowstart = (int*)A((size_t)(NN + 1) * 4);
  int* fill = (int*)A((size_t)NN * 4);
  int* bsum = (int*)A((size_t)64 * 4);
  int* csrS = (int*)A((size_t)EE * 4);
  int* csrE = (int*)A((size_t)EE * 4);
  (void)ws_size; (void)n_in; (void)in_sizes; (void)out_size;

  const int GE = ngrid(EE), GN = ngrid(NN);
  const dim3 RG(32, BB);  // global-round grid: 32 blocks x 8 graphs

  // ===== stage 1: GCNConv(384->6) + ReLU =====
  hipMemsetAsync(htab, 0xFF, (size_t)HT_SIZE * 8, stream);
  hipLaunchKernelGGL(k_mm1, dim3((NN + 3) / 4), dim3(TPB), 0, stream, x, W1, h1pre);
  hipLaunchKernelGGL(k_prep, dim3(GN), dim3(TPB), 0, stream, deg, hasloop, gcntsA, gcntsB,
                     gsum, gcnt, (const unsigned char*)nullptr, nv1, scale, merged, partner, bestA, bestB, remG);
  hipLaunchKernelGGL(k_deg, dim3(GE), dim3(TPB), 0, stream, src, dst, (const unsigned char*)nullptr, deg, hasloop);
  hipLaunchKernelGGL(k_scan1, dim3(NBLK), dim3(SCAN_B), 0, stream, deg, rowstart, bsum);
  hipLaunchKernelGGL(k_scan3, dim3(GN), dim3(TPB), 0, stream, rowstart, bsum, fill, deg, hasloop,
                     (const unsigned char*)nullptr, dinv, addloop);
  hipLaunchKernelGGL(k_scatter, dim3(GE), dim3(TPB), 0, stream, src, dst, (const unsigned char*)nullptr, fill, csrS, csrE);
  hipLaunchKernelGGL(k_agg_fin<HH>, dim3(GN), dim3(TPB), 0, stream, rowstart, csrS, dinv, addloop, h1pre, b1, Wp1, aout, h1out, 1);

  // ===== edge pool 1 =====
  hipLaunchKernelGGL(k_smscore, dim3(GN), dim3(TPB), 0, stream, rowstart, csrS, csrE, aout, remG, score, bestA);
  hipLaunchKernelGGL(k_r1sel, dim3(GE), dim3(TPB), 0, stream, src, dst, score, (const unsigned char*)nullptr, remG, bestA, bestB,
                     nv1, scale, partner, merged, recs0, gcntsA);
  // global rounds 2-6 (split post/sel — R7 lesson: fusing stalls commits)
  hipLaunchKernelGGL(k_gpost, RG, dim3(TPB), 0, stream, recs0, gcntsA, remG, bestB, gcntsB);
  hipLaunchKernelGGL(k_gsel, RG, dim3(TPB), 0, stream, recs0, gcntsA, remG, bestB, bestA, nv1, scale, partner, merged, recs1, gcntsB);
  hipLaunchKernelGGL(k_gpost, RG, dim3(TPB), 0, stream, recs1, gcntsB, remG, bestA, gcntsA);
  hipLaunchKernelGGL(k_gsel, RG, dim3(TPB), 0, stream, recs1, gcntsB, remG, bestA, bestB, nv1, scale, partner, merged, recs0, gcntsA);
  hipLaunchKernelGGL(k_gpost, RG, dim3(TPB), 0, stream, recs0, gcntsA, remG, bestB, gcntsB);
  hipLaunchKernelGGL(k_gsel, RG, dim3(TPB), 0, stream, recs0, gcntsA, remG, bestB, bestA, nv1, scale, partner, merged, recs1, gcntsB);
  hipLaunchKernelGGL(k_gpost, RG, dim3(TPB), 0, stream, recs1, gcntsB, remG, bestA, gcntsA);
  hipLaunchKernelGGL(k_gsel, RG, dim3(TPB), 0, stream, recs1, gcntsB, remG, bestA, bestB, nv1, scale, partner, merged, recs0, gcntsA);
  hipLaunchKernelGGL(k_gpost, RG, dim3(TPB), 0, stream, recs0, gcntsA, remG, bestB, gcntsB);
  hipLaunchKernelGGL(k_gsel, RG, dim3(TPB), 0, stream, recs0, gcntsA, remG, bestB, bestA, nv1, scale, partner, merged, recs1, gcntsB);
  // LDS tail (commits write pool state directly)
  hipLaunchKernelGGL(k_match_g, dim3(BB), dim3(1024), 0, stream, recs1, recs0, gcntsB, remG, nv1, scale, partner, merged);
  hipLaunchKernelGGL(k_newx_prep, dim3(GN), dim3(TPB), 0, stream, h1out, W2, h2pre,
                     deg, hasloop, gcntsA, gcntsB, gsum, gcnt, nv1, nv2, scale, partner, bestA, bestB, remG);
  hipLaunchKernelGGL(k_remap_ins, dim3(GE), dim3(TPB), 0, stream, src, dst, merged, ns, nd, htab);

  // ===== stage 2: GCNConv(6->10) =====
  hipLaunchKernelGGL(k_dedup_deg, dim3(GE), dim3(TPB), 0, stream, ns, nd, htab, ev1, deg, hasloop);
  hipLaunchKernelGGL(k_scan1, dim3(NBLK), dim3(SCAN_B), 0, stream, deg, rowstart, bsum);
  hipLaunchKernelGGL(k_scan3, dim3(GN), dim3(TPB), 0, stream, rowstart, bsum, fill, deg, hasloop,
                     (const unsigned char*)nv1, dinv, addloop);
  hipLaunchKernelGGL(k_scatter, dim3(GE), dim3(TPB), 0, stream, ns, nd, (const unsigned char*)ev1, fill, csrS, csrE);
  hipLaunchKernelGGL(k_agg_fin<CC>, dim3(GN), dim3(TPB), 0, stream, rowstart, csrS, dinv, addloop, h2pre, b2, Wp2, aout, h2out, 0);

  // ===== edge pool 2 =====
  hipLaunchKernelGGL(k_smscore, dim3(GN), dim3(TPB), 0, stream, rowstart, csrS, csrE, aout, remG, score, bestA);
  hipLaunchKernelGGL(k_r1sel, dim3(GE), dim3(TPB), 0, stream, ns, nd, score, (const unsigned char*)ev1, remG, bestA, bestB,
                     nv2, scale, partner, (int*)nullptr, recs0, gcntsA);
  hipLaunchKernelGGL(k_gpost, RG, dim3(TPB), 0, stream, recs0, gcntsA, remG, bestB, gcntsB);
  hipLaunchKernelGGL(k_gsel, RG, dim3(TPB), 0, stream, recs0, gcntsA, remG, bestB, bestA, nv2, scale, partner, (int*)nullptr, recs1, gcntsB);
  hipLaunchKernelGGL(k_gpost, RG, dim3(TPB), 0, stream, recs1, gcntsB, remG, bestA, gcntsA);
  hipLaunchKernelGGL(k_gsel, RG, dim3(TPB), 0, stream, recs1, gcntsB, remG, bestA, bestB, nv2, scale, partner, (int*)nullptr, recs0, gcntsA);
  hipLaunchKernelGGL(k_gpost, RG, dim3(TPB), 0, stream, recs0, gcntsA, remG, bestB, gcntsB);
  hipLaunchKernelGGL(k_gsel, RG, dim3(TPB), 0, stream, recs0, gcntsA, remG, bestB, bestA, nv2, scale, partner, (int*)nullptr, recs1, gcntsB);
  hipLaunchKernelGGL(k_gpost, RG, dim3(TPB), 0, stream, recs1, gcntsB, remG, bestA, gcntsA);
  hipLaunchKernelGGL(k_gsel, RG, dim3(TPB), 0, stream, recs1, gcntsB, remG, bestA, bestB, nv2, scale, partner, (int*)nullptr, recs0, gcntsA);
  hipLaunchKernelGGL(k_gpost, RG, dim3(TPB), 0, stream, recs0, gcntsA, remG, bestB, gcntsB);
  hipLaunchKernelGGL(k_gsel, RG, dim3(TPB), 0, stream, recs0, gcntsA, remG, bestB, bestA, nv2, scale, partner, (int*)nullptr, recs1, gcntsB);
  hipLaunchKernelGGL(k_match_g, dim3(BB), dim3(1024), 0, stream, recs1, recs0, gcntsB, remG, nv2, scale, partner, (int*)nullptr);

  // ===== readout =====
  hipLaunchKernelGGL(k_newx_pool, dim3(GN), dim3(TPB), 0, stream, h2out, partner, scale, nv2, gsum, gcnt);
  hipLaunchKernelGGL(k_logsm, dim3(1), dim3(64), 0, stream, gsum, gcnt, out);
}